// Round 9
// baseline (598.024 us; speedup 1.0000x reference)
//
#include <hip/hip_runtime.h>
#include <hip/hip_fp8.h>

#define N_NODES 100000
#define N_EDGES 1600000
#define BN_EPS 1e-5f
#define E4 400000        // N_EDGES / 4 (int4 count)
#define D1_BLOCKS 1563   // ceil(100000/64)
#define CAP 64           // bucket capacity; P(deg>64) ~ 1e-20/node (Poisson 16)
#define NBINS 391        // bins of 256 nodes: bin = dst >> 8 (max 99999>>8 = 390)
#define BINCAP 4608      // mean 4096 + 8 sigma
#define BIN_MASK 255
#define GBLK 1563        // gather1 node-chunks; grid = GBLK*8 feature groups

typedef float v2f __attribute__((ext_vector_type(2)));

// broadcast lane k's value (readlane). Wave-uniform control flow ONLY.
__device__ __forceinline__ float bcast(float v, int k) {
    return __uint_as_float(__builtin_amdgcn_readlane(__float_as_uint(v), k));
}
// fp8 e4m3 encode (cold path: once per element in the dense kernels)
__device__ __forceinline__ unsigned char f2fp8(float x) {
    return (unsigned char)__hip_cvt_float_to_fp8(x, __HIP_SATFINITE, __HIP_E4M3);
}
// HW packed decode: 2 x fp8(e4m3) -> 2 x f32 in ONE VALU instruction.
template <bool HI>
__device__ __forceinline__ v2f fp8x2(unsigned int w) {
#if __has_builtin(__builtin_amdgcn_cvt_pk_f32_fp8)
    return __builtin_amdgcn_cvt_pk_f32_fp8((int)w, HI);
#else
    unsigned int b = HI ? (w >> 16) : w;
    __half_raw h0 = __hip_cvt_fp8_to_halfraw((__hip_fp8_storage_t)(b & 0xFF), __HIP_E4M3);
    __half_raw h1 = __hip_cvt_fp8_to_halfraw((__hip_fp8_storage_t)((b >> 8) & 0xFF), __HIP_E4M3);
    v2f r; r.x = __half2float(__half(h0)); r.y = __half2float(__half(h1));
    return r;
#endif
}

// ===========================================================================
// binA (R22 proven): radix partition into 391 coarse bins; LDS counting +
// one bulk global claim per bin per block. binbuf lives in d_out.
// ===========================================================================
__global__ __launch_bounds__(1024) void binA_kernel(
    const int4* __restrict__ src4, const int4* __restrict__ dst4,
    int* __restrict__ bcur, unsigned int* __restrict__ binbuf)
{
    __shared__ int lcnt[NBINS];
    __shared__ int lbase[NBINS];
    int tid = threadIdx.x;
    if (tid < NBINS) lcnt[tid] = 0;
    __syncthreads();

    int i = blockIdx.x * 1024 + tid;
    int4 d, s;
    int b0 = 0, b1 = 0, b2 = 0, b3 = 0, r0 = 0, r1 = 0, r2 = 0, r3 = 0;
    bool valid = (i < E4);
    if (valid) {
        d = dst4[i]; s = src4[i];
        b0 = d.x >> 8; r0 = atomicAdd(&lcnt[b0], 1);
        b1 = d.y >> 8; r1 = atomicAdd(&lcnt[b1], 1);
        b2 = d.z >> 8; r2 = atomicAdd(&lcnt[b2], 1);
        b3 = d.w >> 8; r3 = atomicAdd(&lcnt[b3], 1);
    }
    __syncthreads();
    if (tid < NBINS && lcnt[tid] > 0)
        lbase[tid] = atomicAdd(&bcur[tid], lcnt[tid]);
    __syncthreads();
    if (valid) {
        int p;
        p = lbase[b0] + r0; if (p < BINCAP) binbuf[(size_t)b0 * BINCAP + p] = ((unsigned)s.x << 8) | (unsigned)(d.x & BIN_MASK);
        p = lbase[b1] + r1; if (p < BINCAP) binbuf[(size_t)b1 * BINCAP + p] = ((unsigned)s.y << 8) | (unsigned)(d.y & BIN_MASK);
        p = lbase[b2] + r2; if (p < BINCAP) binbuf[(size_t)b2 * BINCAP + p] = ((unsigned)s.z << 8) | (unsigned)(d.z & BIN_MASK);
        p = lbase[b3] + r3; if (p < BINCAP) binbuf[(size_t)b3 * BINCAP + p] = ((unsigned)s.w << 8) | (unsigned)(d.w & BIN_MASK);
    }
}

// ===========================================================================
// binB + dense1 FUSED (R22 proven structure). R23 change: dense1 stores the
// layer-1 activations TRANSPOSED: u8T[g][node][8B] (fp8) and hvT[g][node][8]
// (f32), g = f>>3 -- so gather1 can run 8 XCD-pinned feature-group sweeps
// whose 800KB table slice is per-XCD L2-RESIDENT (today's 6.4MB table misses
// L2 ~50%, and rocprof shows L3 does not retain it: ~47MB of u8 HBM fetches).
// u8T rows packed to ONE 8B store per 8 lanes via shuffles.
// ===========================================================================
__global__ __launch_bounds__(256) void binB_dense1_kernel(
    const unsigned int* __restrict__ binbuf, const int* __restrict__ bcur,
    int* __restrict__ cnt, int* __restrict__ nbrf,
    const float* __restrict__ x, const float* __restrict__ W1l,
    const float* __restrict__ W1r, const float* __restrict__ b1,
    unsigned char* __restrict__ u8T, float* __restrict__ hvT)
{
    __shared__ float wlT[64 * 65];
    __shared__ float wrT[64 * 65];

    if (blockIdx.x < NBINS) {
        // ---- binB role: per-bin bucket build with LDS slot counters ----
        __shared__ int lc[256];
        int tid = threadIdx.x;
        lc[tid] = 0;
        __syncthreads();
        int bin = blockIdx.x;
        int n = min(bcur[bin], BINCAP);
        for (int i = tid; i < n; i += 256) {
            unsigned int e = binbuf[(size_t)bin * BINCAP + i];
            int dl  = (int)(e & BIN_MASK);
            int src = (int)(e >> 8);
            int slot = atomicAdd(&lc[dl], 1);          // LDS atomic
            if (slot < CAP)
                nbrf[((size_t)(bin * 256 + dl)) * CAP + slot] = src;
        }
        __syncthreads();
        int node = bin * 256 + tid;
        if (node < N_NODES) {
            int c = min(lc[tid], CAP);
            cnt[node] = c;
            if (c == 0) nbrf[(size_t)node * CAP] = 0;  // safe id for deg==0
        }
        return;
    }

    // ---- dense1 role ----
    for (int idx = threadIdx.x; idx < 4096; idx += 256) {
        int f = idx >> 6, k = idx & 63;
        wlT[k * 65 + f] = W1l[idx];
        wrT[k * 65 + f] = W1r[idx];
    }
    __syncthreads();

    int f  = threadIdx.x & 63;
    int wv = threadIdx.x >> 6;
    int g  = f >> 3;               // feature group 0..7
    int fg = f & 7;                // feature within group
    float wl[64], wr[64];
#pragma unroll
    for (int k = 0; k < 64; ++k) {
        wl[k] = wlT[k * 65 + f];
        wr[k] = wrT[k * 65 + f];
    }
    float bias = b1[f];
    int node0 = (blockIdx.x - NBINS) * 64;

    for (int nn = 0; nn < 16; ++nn) {
        int node = node0 + nn * 4 + wv;          // wave-uniform
        if (node < N_NODES) {
            float xv = x[(size_t)node * 64 + f];
            float ua = 0.f, va = bias;
#pragma unroll
            for (int k = 0; k < 64; ++k) {
                float xb = bcast(xv, k);
                ua += xb * wl[k];
                va += xb * wr[k];
            }
            // pack 8 fp8 bytes (lanes f..f+7 of this group) -> one 8B store
            unsigned int b = (unsigned int)f2fp8(ua);
            unsigned long long pk = (unsigned long long)b;
#pragma unroll
            for (int k = 1; k < 8; ++k)
                pk |= (unsigned long long)((unsigned)__shfl_down((int)b, k) & 0xFFu) << (8 * k);
            if (fg == 0)
                *(unsigned long long*)(u8T + ((size_t)g * N_NODES + node) * 8) = pk;
            hvT[((size_t)g * N_NODES + node) * 8 + fg] = va;
        }
    }
}

// ===========================================================================
// gather1_bn v13 (R23): 8 feature-group sweeps, g = blockIdx&7 (round-robin
// -> XCD g), node-chunk = blockIdx>>3. Per node: ONE 64-lane dword load
// covers 32 edges x 8B slice (lane pair per edge); 5-level butterfly reduces
// the edge dimension. u8T slice (800KB) is per-XCD L2-resident. v10's id
// prefetch + hoisted hv read retained. deg>32 rare second round inline.
// ===========================================================================
__global__ __launch_bounds__(256) void gather1_bn_kernel(
    const unsigned char* __restrict__ u8T, const int* __restrict__ cnt,
    const int* __restrict__ nbrf, float* __restrict__ hvT,
    float* __restrict__ sums, float* __restrict__ sumsq)
{
    __shared__ int sdeg[64];
    __shared__ float4 rA[4][2];
    __shared__ float4 rB[4][2];

    int g     = blockIdx.x & 7;
    int node0 = (blockIdx.x >> 3) * 64;
    if (threadIdx.x < 64) {
        int n = node0 + threadIdx.x;
        sdeg[threadIdx.x] = (n < N_NODES) ? min(cnt[n], CAP) : 0;
    }
    __syncthreads();

    int lane  = threadIdx.x & 63;
    int e     = lane >> 1;        // edge slot 0..31
    int half8 = lane & 1;         // dword within the 8B slice
    int wv    = threadIdx.x >> 6;

    const unsigned char* u8g = u8T + (size_t)g * N_NODES * 8;
    float* hvg = hvT + (size_t)g * N_NODES * 8;

    float s1_0=0,s1_1=0,s1_2=0,s1_3=0, s2_0=0,s2_1=0,s2_2=0,s2_3=0;

    // prefetch ids for the first node (clamped; safe for deg==0)
    int d0  = sdeg[wv];
    int idn = nbrf[(size_t)min(node0 + wv, N_NODES - 1) * CAP + min(e, max(d0, 1) - 1)];

    for (int nn = 0; nn < 16; ++nn) {
        int li   = nn * 4 + wv;
        int node = node0 + li;
        int deg  = sdeg[li];
        int id   = idn;

        // prefetch next node's ids while this node's row loads/decodes
        if (nn < 15) {
            int lin = li + 4;
            int dn  = sdeg[lin];
            idn = nbrf[(size_t)min(node0 + lin, N_NODES - 1) * CAP + min(e, max(dn, 1) - 1)];
        }

        if (node < N_NODES) {                    // wave-uniform
            // hoisted hv read (lanes 0,1): overlaps the row-load latency
            float4 v = make_float4(0.f, 0.f, 0.f, 0.f);
            if (lane < 2)
                v = *(const float4*)(hvg + (size_t)node * 8 + half8 * 4);

            unsigned int w = *(const unsigned int*)(u8g + (size_t)id * 8 + (half8 << 2));
            w = (e < deg) ? w : 0u;
            v2f dlo = fp8x2<false>(w);
            v2f dhi = fp8x2<true>(w);
            float a0 = dlo.x, a1 = dlo.y, a2 = dhi.x, a3 = dhi.y;

            if (deg > 32) {                      // rare, wave-uniform
                int e2  = 32 + e;
                int id2 = nbrf[(size_t)node * CAP + min(e2, deg - 1)];
                unsigned int w2 = *(const unsigned int*)(u8g + (size_t)id2 * 8 + (half8 << 2));
                w2 = (e2 < deg) ? w2 : 0u;
                v2f l2 = fp8x2<false>(w2);
                v2f m2 = fp8x2<true>(w2);
                a0 += l2.x; a1 += l2.y; a2 += m2.x; a3 += m2.y;
            }
            // butterfly over the edge dimension (strides 2..32; bit0 = half8)
            a0 += __shfl_xor(a0, 2);  a1 += __shfl_xor(a1, 2);  a2 += __shfl_xor(a2, 2);  a3 += __shfl_xor(a3, 2);
            a0 += __shfl_xor(a0, 4);  a1 += __shfl_xor(a1, 4);  a2 += __shfl_xor(a2, 4);  a3 += __shfl_xor(a3, 4);
            a0 += __shfl_xor(a0, 8);  a1 += __shfl_xor(a1, 8);  a2 += __shfl_xor(a2, 8);  a3 += __shfl_xor(a3, 8);
            a0 += __shfl_xor(a0, 16); a1 += __shfl_xor(a1, 16); a2 += __shfl_xor(a2, 16); a3 += __shfl_xor(a3, 16);
            a0 += __shfl_xor(a0, 32); a1 += __shfl_xor(a1, 32); a2 += __shfl_xor(a2, 32); a3 += __shfl_xor(a3, 32);

            if (lane < 2) {
                float inv = 1.0f / (float)max(deg, 1);
                float h0 = a0 * inv + v.x;
                float h1 = a1 * inv + v.y;
                float h2 = a2 * inv + v.z;
                float h3 = a3 * inv + v.w;
                *(float4*)(hvg + (size_t)node * 8 + half8 * 4) = make_float4(h0, h1, h2, h3);
                s1_0 += h0; s1_1 += h1; s1_2 += h2; s1_3 += h3;
                s2_0 += h0 * h0; s2_1 += h1 * h1; s2_2 += h2 * h2; s2_3 += h3 * h3;
            }
        }
    }

    if (lane < 2) {
        rA[wv][half8] = make_float4(s1_0, s1_1, s1_2, s1_3);
        rB[wv][half8] = make_float4(s2_0, s2_1, s2_2, s2_3);
    }
    __syncthreads();
    if (threadIdx.x < 2) {
        int h = threadIdx.x;
        float4 A = rA[0][h], B = rB[0][h];
        for (int w2 = 1; w2 < 4; ++w2) {
            A.x += rA[w2][h].x; A.y += rA[w2][h].y; A.z += rA[w2][h].z; A.w += rA[w2][h].w;
            B.x += rB[w2][h].x; B.y += rB[w2][h].y; B.z += rB[w2][h].z; B.w += rB[w2][h].w;
        }
        int f = g * 8 + h * 4;
        atomicAdd(&sums[f + 0], A.x);  atomicAdd(&sums[f + 1], A.y);
        atomicAdd(&sums[f + 2], A.z);  atomicAdd(&sums[f + 3], A.w);
        atomicAdd(&sumsq[f + 0], B.x); atomicAdd(&sumsq[f + 1], B.y);
        atomicAdd(&sumsq[f + 2], B.z); atomicAdd(&sumsq[f + 3], B.w);
    }
}

// ===========================================================================
// dense2_bn: unchanged math; h now read from the transposed hvT layout.
// ===========================================================================
__global__ __launch_bounds__(256) void dense2_bn_kernel(
    const float* __restrict__ hvT, const float* __restrict__ sums,
    const float* __restrict__ sumsq, const float* __restrict__ gamma,
    const float* __restrict__ beta, const float* __restrict__ W2l,
    const float* __restrict__ W2r, const float* __restrict__ b2,
    unsigned char* __restrict__ t40, float* __restrict__ out)
{
    __shared__ float wlT[64 * 65];
    __shared__ float wrT[64 * 65];
    for (int idx = threadIdx.x; idx < 2560; idx += 256) {
        int f = idx >> 6, k = idx & 63;      // f < 40
        wlT[k * 65 + f] = W2l[idx];
        wrT[k * 65 + f] = W2r[idx];
    }
    __syncthreads();

    int f  = threadIdx.x & 63;
    int wv = threadIdx.x >> 6;
    int fc = (f < 40) ? f : 39;
    float wl[64], wr[64];
#pragma unroll
    for (int k = 0; k < 64; ++k) {
        wl[k] = wlT[k * 65 + fc];
        wr[k] = wrT[k * 65 + fc];
    }
    float bias = b2[fc];

    // BN finalize (redundant per block, ~10 insts)
    float inv_n = 1.0f / (float)N_NODES;
    float mu  = sums[f] * inv_n;
    float var = sumsq[f] * inv_n - mu * mu;
    float rs  = rsqrtf(var + BN_EPS);
    float sc  = gamma[f] * rs;
    float sh  = beta[f] - mu * sc;

    int g  = f >> 3;
    int fg = f & 7;
    int node0 = blockIdx.x * 64;

    for (int nn = 0; nn < 16; ++nn) {
        int node = node0 + nn * 4 + wv;          // wave-uniform
        if (node < N_NODES) {
            float hvv = hvT[((size_t)g * N_NODES + node) * 8 + fg];
            float hn  = fmaxf(hvv * sc + sh, 0.f);   // BN + ReLU fused
            float ta = 0.f, ra = bias;
#pragma unroll
            for (int k = 0; k < 64; ++k) {
                float hb = bcast(hn, k);
                ta += hb * wl[k];
                ra += hb * wr[k];
            }
            if (f < 40) {
                t40[(size_t)node * 64 + f] = f2fp8(ta);
                out[(size_t)node * 40 + f] = ra;
            }
        }
    }
}

// ===========================================================================
// gather2 v10 (R21 proven, UNCHANGED): v9 pipelined structure on buckets.
// ===========================================================================
__global__ __launch_bounds__(256) void gather2_kernel(
    const unsigned int* __restrict__ t40, const int* __restrict__ cnt,
    const int* __restrict__ nbrf, float* __restrict__ out)
{
    __shared__ int sdeg[64];
    int node0 = blockIdx.x * 64;
    if (threadIdx.x < 64) {
        int n = node0 + threadIdx.x;
        sdeg[threadIdx.x] = (n < N_NODES) ? min(cnt[n], CAP) : 0;
    }
    __syncthreads();

    int lane = threadIdx.x & 63;
    int q    = lane >> 4;          // quarter 0..3
    int m    = lane & 15;          // dword in row; cl<10 used
    int cl   = (m < 10) ? m : 9;
    int wv   = threadIdx.x >> 6;

    int dA = sdeg[wv], dB = sdeg[wv + 4];
    int idA = nbrf[(size_t)min(node0 + wv,     N_NODES - 1) * CAP + min(lane, max(dA, 1) - 1)];
    int idB = nbrf[(size_t)min(node0 + wv + 4, N_NODES - 1) * CAP + min(lane, max(dB, 1) - 1)];

    unsigned int r0A[4], r1A[4], r0B[4], r1B[4];
    {
        int cnt0 = dA;
#pragma unroll
        for (int i = 0; i < 4; ++i) {
            int e   = 4 * i + q;
            int ide = __shfl(idA, max(min(e, cnt0 - 1), 0));
            r0A[i] = t40[(size_t)ide * 16 + cl];
        }
        if (cnt0 > 16) {
#pragma unroll
            for (int i = 0; i < 4; ++i) {
                int e   = 16 + 4 * i + q;
                int ide = __shfl(idA, min(e, cnt0 - 1));
                r1A[i] = t40[(size_t)ide * 16 + cl];
            }
        }
    }

    for (int nn = 0; nn < 16; ++nn) {
        int li   = nn * 4 + wv;
        int node = node0 + li;
        int deg  = sdeg[li];

        int idC = 0;
        if (nn < 14) {
            int lic = li + 8;
            int dc  = sdeg[lic];
            idC = nbrf[(size_t)min(node0 + lic, N_NODES - 1) * CAP + min(lane, max(dc, 1) - 1)];
        }
        if (nn < 15) {
            int cntn = sdeg[li + 4];
#pragma unroll
            for (int i = 0; i < 4; ++i) {
                int e   = 4 * i + q;
                int ide = __shfl(idB, max(min(e, cntn - 1), 0));
                r0B[i] = t40[(size_t)ide * 16 + cl];
            }
            if (cntn > 16) {
#pragma unroll
                for (int i = 0; i < 4; ++i) {
                    int e   = 16 + 4 * i + q;
                    int ide = __shfl(idB, min(e, cntn - 1));
                    r1B[i] = t40[(size_t)ide * 16 + cl];
                }
            }
        }

        if (node < N_NODES) {                    // wave-uniform
            float4 o = make_float4(0.f, 0.f, 0.f, 0.f);
            if (lane < 10)
                o = ((const float4*)out)[(size_t)node * 10 + m];

            float a0=0,a1=0,a2=0,a3=0, b0=0,b1=0,b2=0,b3=0;
            // round 0 from prefetched regs
#pragma unroll
            for (int i = 0; i < 4; ++i) {
                int e = 4 * i + q;
                unsigned int w = (e < deg) ? r0A[i] : 0u;
                v2f dlo = fp8x2<false>(w);
                v2f dhi = fp8x2<true>(w);
                if (i & 1) { b0 += dlo.x; b1 += dlo.y; b2 += dhi.x; b3 += dhi.y; }
                else       { a0 += dlo.x; a1 += dlo.y; a2 += dhi.x; a3 += dhi.y; }
            }
            if (deg > 16) {                      // wave-uniform
#pragma unroll
                for (int i = 0; i < 4; ++i) {
                    int e = 16 + 4 * i + q;
                    unsigned int w = (e < deg) ? r1A[i] : 0u;
                    v2f dlo = fp8x2<false>(w);
                    v2f dhi = fp8x2<true>(w);
                    if (i & 1) { b0 += dlo.x; b1 += dlo.y; b2 += dhi.x; b3 += dhi.y; }
                    else       { a0 += dlo.x; a1 += dlo.y; a2 += dhi.x; a3 += dhi.y; }
                }
                for (int r = 32; r < deg; r += 16) {
#pragma unroll
                    for (int i = 0; i < 4; ++i) {
                        int e   = r + 4 * i + q;
                        int ide = __shfl(idA, min(e, deg - 1));
                        unsigned int w = t40[(size_t)ide * 16 + cl];
                        w = (e < deg) ? w : 0u;
                        v2f dlo = fp8x2<false>(w);
                        v2f dhi = fp8x2<true>(w);
                        if (i & 1) { b0 += dlo.x; b1 += dlo.y; b2 += dhi.x; b3 += dhi.y; }
                        else       { a0 += dlo.x; a1 += dlo.y; a2 += dhi.x; a3 += dhi.y; }
                    }
                }
            }
            a0 += b0; a1 += b1; a2 += b2; a3 += b3;
            a0 += __shfl_xor(a0, 16); a0 += __shfl_xor(a0, 32);
            a1 += __shfl_xor(a1, 16); a1 += __shfl_xor(a1, 32);
            a2 += __shfl_xor(a2, 16); a2 += __shfl_xor(a2, 32);
            a3 += __shfl_xor(a3, 16); a3 += __shfl_xor(a3, 32);
            if (lane < 10) {
                float inv = 1.0f / (float)max(deg, 1);
                o.x += a0 * inv;
                o.y += a1 * inv;
                o.z += a2 * inv;
                o.w += a3 * inv;
                ((float4*)out)[(size_t)node * 10 + m] = o;
            }
        }

        idA = idB; idB = idC;
#pragma unroll
        for (int i = 0; i < 4; ++i) { r0A[i] = r0B[i]; r1A[i] = r1B[i]; }
    }
}

extern "C" void kernel_launch(void* const* d_in, const int* in_sizes, int n_in,
                              void* d_out, int out_size, void* d_ws, size_t ws_size,
                              hipStream_t stream)
{
    const float* x     = (const float*)d_in[0];
    const int*   ei    = (const int*)d_in[1];
    const float* W1l   = (const float*)d_in[2];
    const float* W1r   = (const float*)d_in[3];
    const float* b1    = (const float*)d_in[4];
    const float* gamma = (const float*)d_in[5];
    const float* beta  = (const float*)d_in[6];
    const float* W2l   = (const float*)d_in[7];
    const float* W2r   = (const float*)d_in[8];
    const float* b2    = (const float*)d_in[9];
    float* out = (float*)d_out;

    const int4* src4 = (const int4*)ei;              // edge_index[0], 16B-aligned
    const int4* dst4 = (const int4*)(ei + N_EDGES);  // edge_index[1]

    // workspace layout (58.0 MB of 58.8), 64B-aligned arrays:
    // hvT[8][N][8] f32 | sums 64 | sumsq 64 | pad 128 | bcur 392 | cnt[N] |
    // nbrf[N*64] int | u8T[8][N][8] fp8 (t40 reuses it).
    // binbuf (7.2 MB) lives in d_out -- scratch until dense2 writes out.
    float* ws    = (float*)d_ws;
    float* hvT   = ws;                               // 25.6 MB
    float* sums  = hvT + (size_t)N_NODES * 64;       // 64
    float* sumsq = sums + 64;                        // 64
    float* padf  = sumsq + 64;                       // 128 pad
    int* bcur = (int*)(padf + 128);                  // 392 (391 used)
    int* cnt  = bcur + 392;                          // N
    int* nbrf = cnt + N_NODES;                       // N*64 (25.6 MB)
    unsigned char* u8T = (unsigned char*)(nbrf + (size_t)N_NODES * 64);  // 6.4 MB
    unsigned char* t40 = u8T;
    unsigned int* binbuf = (unsigned int*)d_out;     // 391*4608*4 = 7.2 MB

    dim3 blk(256);

    // zero sums|sumsq|pad|bcur only (cnt written exactly by binB): 2592 B
    (void)hipMemsetAsync(sums, 0, (size_t)(64 + 64 + 128 + 392) * 4, stream);

    int gblocks = (N_NODES + 63) / 64;

    // ---- edge radix partition (391 coarse bins) ----
    binA_kernel<<<391, 1024, 0, stream>>>(src4, dst4, bcur, binbuf);

    // ---- per-bin bucket build (LDS atomics) + layer-1 dense, FUSED ----
    binB_dense1_kernel<<<NBINS + D1_BLOCKS, blk, 0, stream>>>(
        binbuf, bcur, cnt, nbrf, x, W1l, W1r, b1, u8T, hvT);

    // ---- layer-1 gather: 8 XCD-pinned feature-group sweeps ----
    gather1_bn_kernel<<<GBLK * 8, blk, 0, stream>>>(
        u8T, cnt, nbrf, hvT, sums, sumsq);

    // ---- layer 2 (BN finalize + BN+ReLU fused into dense2) ----
    dense2_bn_kernel<<<gblocks, blk, 0, stream>>>(
        hvT, sums, sumsq, gamma, beta, W2l, W2r, b2, t40, out);
    gather2_kernel<<<gblocks, blk, 0, stream>>>(
        (const unsigned int*)t40, cnt, nbrf, out);
}

// Round 10
// 557.793 us; speedup vs baseline: 1.0721x; 1.0721x over previous
//
#include <hip/hip_runtime.h>
#include <hip/hip_fp8.h>

#define N_NODES 100000
#define N_EDGES 1600000
#define BN_EPS 1e-5f
#define E4 400000        // N_EDGES / 4 (int4 count)
#define D1_BLOCKS 1563   // ceil(100000/64)
#define CAP 64           // bucket capacity; P(deg>64) ~ 1e-20/node (Poisson 16)
#define NBINS 391        // bins of 256 nodes: bin = dst >> 8 (max 99999>>8 = 390)
#define BINCAP 4608      // mean 4096 + 8 sigma
#define BIN_MASK 255
#define G_BLOCKS 6250    // gathers: 16 nodes/block (exact: 6250*16 = 100000)

typedef float v2f __attribute__((ext_vector_type(2)));

// broadcast lane k's value (readlane). Wave-uniform control flow ONLY.
__device__ __forceinline__ float bcast(float v, int k) {
    return __uint_as_float(__builtin_amdgcn_readlane(__float_as_uint(v), k));
}
// fp8 e4m3 encode (cold path: once per element in the dense kernels)
__device__ __forceinline__ unsigned char f2fp8(float x) {
    return (unsigned char)__hip_cvt_float_to_fp8(x, __HIP_SATFINITE, __HIP_E4M3);
}
// HW packed decode: 2 x fp8(e4m3) -> 2 x f32 in ONE VALU instruction.
template <bool HI>
__device__ __forceinline__ v2f fp8x2(unsigned int w) {
#if __has_builtin(__builtin_amdgcn_cvt_pk_f32_fp8)
    return __builtin_amdgcn_cvt_pk_f32_fp8((int)w, HI);
#else
    unsigned int b = HI ? (w >> 16) : w;
    __half_raw h0 = __hip_cvt_fp8_to_halfraw((__hip_fp8_storage_t)(b & 0xFF), __HIP_E4M3);
    __half_raw h1 = __hip_cvt_fp8_to_halfraw((__hip_fp8_storage_t)((b >> 8) & 0xFF), __HIP_E4M3);
    v2f r; r.x = __half2float(__half(h0)); r.y = __half2float(__half(h1));
    return r;
#endif
}

// ===========================================================================
// binA (R22 proven): radix partition into 391 coarse bins; LDS counting +
// one bulk global claim per bin per block. binbuf lives in d_out.
// ===========================================================================
__global__ __launch_bounds__(1024) void binA_kernel(
    const int4* __restrict__ src4, const int4* __restrict__ dst4,
    int* __restrict__ bcur, unsigned int* __restrict__ binbuf)
{
    __shared__ int lcnt[NBINS];
    __shared__ int lbase[NBINS];
    int tid = threadIdx.x;
    if (tid < NBINS) lcnt[tid] = 0;
    __syncthreads();

    int i = blockIdx.x * 1024 + tid;
    int4 d, s;
    int b0 = 0, b1 = 0, b2 = 0, b3 = 0, r0 = 0, r1 = 0, r2 = 0, r3 = 0;
    bool valid = (i < E4);
    if (valid) {
        d = dst4[i]; s = src4[i];
        b0 = d.x >> 8; r0 = atomicAdd(&lcnt[b0], 1);
        b1 = d.y >> 8; r1 = atomicAdd(&lcnt[b1], 1);
        b2 = d.z >> 8; r2 = atomicAdd(&lcnt[b2], 1);
        b3 = d.w >> 8; r3 = atomicAdd(&lcnt[b3], 1);
    }
    __syncthreads();
    if (tid < NBINS && lcnt[tid] > 0)
        lbase[tid] = atomicAdd(&bcur[tid], lcnt[tid]);
    __syncthreads();
    if (valid) {
        int p;
        p = lbase[b0] + r0; if (p < BINCAP) binbuf[(size_t)b0 * BINCAP + p] = ((unsigned)s.x << 8) | (unsigned)(d.x & BIN_MASK);
        p = lbase[b1] + r1; if (p < BINCAP) binbuf[(size_t)b1 * BINCAP + p] = ((unsigned)s.y << 8) | (unsigned)(d.y & BIN_MASK);
        p = lbase[b2] + r2; if (p < BINCAP) binbuf[(size_t)b2 * BINCAP + p] = ((unsigned)s.z << 8) | (unsigned)(d.z & BIN_MASK);
        p = lbase[b3] + r3; if (p < BINCAP) binbuf[(size_t)b3 * BINCAP + p] = ((unsigned)s.w << 8) | (unsigned)(d.w & BIN_MASK);
    }
}

// ===========================================================================
// binB + dense1 FUSED (R22 proven; R9's transpose REVERTED -- it cut per-wave
// misses-in-flight 8x and regressed 3x). Plain u8/hv layouts.
// ===========================================================================
__global__ __launch_bounds__(256) void binB_dense1_kernel(
    const unsigned int* __restrict__ binbuf, const int* __restrict__ bcur,
    int* __restrict__ cnt, int* __restrict__ nbrf,
    const float* __restrict__ x, const float* __restrict__ W1l,
    const float* __restrict__ W1r, const float* __restrict__ b1,
    unsigned char* __restrict__ u8, float* __restrict__ hv)
{
    __shared__ float wlT[64 * 65];
    __shared__ float wrT[64 * 65];

    if (blockIdx.x < NBINS) {
        // ---- binB role: per-bin bucket build with LDS slot counters ----
        __shared__ int lc[256];
        int tid = threadIdx.x;
        lc[tid] = 0;
        __syncthreads();
        int bin = blockIdx.x;
        int n = min(bcur[bin], BINCAP);
        for (int i = tid; i < n; i += 256) {
            unsigned int e = binbuf[(size_t)bin * BINCAP + i];
            int dl  = (int)(e & BIN_MASK);
            int src = (int)(e >> 8);
            int slot = atomicAdd(&lc[dl], 1);          // LDS atomic
            if (slot < CAP)
                nbrf[((size_t)(bin * 256 + dl)) * CAP + slot] = src;
        }
        __syncthreads();
        int node = bin * 256 + tid;
        if (node < N_NODES) {
            int c = min(lc[tid], CAP);
            cnt[node] = c;
            if (c == 0) nbrf[(size_t)node * CAP] = 0;  // safe id for deg==0
        }
        return;
    }

    // ---- dense1 role ----
    for (int idx = threadIdx.x; idx < 4096; idx += 256) {
        int f = idx >> 6, k = idx & 63;
        wlT[k * 65 + f] = W1l[idx];
        wrT[k * 65 + f] = W1r[idx];
    }
    __syncthreads();

    int f  = threadIdx.x & 63;
    int wv = threadIdx.x >> 6;
    float wl[64], wr[64];
#pragma unroll
    for (int k = 0; k < 64; ++k) {
        wl[k] = wlT[k * 65 + f];
        wr[k] = wrT[k * 65 + f];
    }
    float bias = b1[f];
    int node0 = (blockIdx.x - NBINS) * 64;

    for (int nn = 0; nn < 16; ++nn) {
        int node = node0 + nn * 4 + wv;          // wave-uniform
        if (node < N_NODES) {
            float xv = x[(size_t)node * 64 + f];
            float ua = 0.f, va = bias;
#pragma unroll
            for (int k = 0; k < 64; ++k) {
                float xb = bcast(xv, k);
                ua += xb * wl[k];
                va += xb * wr[k];
            }
            u8[(size_t)node * 64 + f] = f2fp8(ua);   // coalesced 64B/node
            hv[(size_t)node * 64 + f] = va;
        }
    }
}

// ===========================================================================
// gather1_bn v14 (R24): v12 inner structure BYTE-IDENTICAL (8 row-loads in
// flight per round -- the proven per-wave shape); ONLY the node mapping
// changes: 16 nodes/block (was 64) -> grid 6250 = 25K waves vs 6.2K. R9's
// lesson: the controlling quantity is active_waves x misses_in_flight/wave;
// R8 ran at 39% occupancy (grid too small to fill 8192 wave slots). This
// raises the waves factor without touching the per-wave miss window.
// ===========================================================================
__global__ __launch_bounds__(256) void gather1_bn_kernel(
    const unsigned short* __restrict__ u16, const int* __restrict__ cnt,
    const int* __restrict__ nbrf, float* __restrict__ hv,
    float* __restrict__ sums, float* __restrict__ sumsq)
{
    __shared__ int sdeg[16];
    int node0 = blockIdx.x * 16;
    if (threadIdx.x < 16) {
        int n = node0 + threadIdx.x;
        sdeg[threadIdx.x] = (n < N_NODES) ? min(cnt[n], CAP) : 0;
    }
    __syncthreads();

    int lane = threadIdx.x & 63;
    int m    = lane & 31;
    int half = lane >> 5;
    int wv   = threadIdx.x >> 6;
    float s1_0 = 0.f, s1_1 = 0.f, s2_0 = 0.f, s2_1 = 0.f;

    // prefetch ids for the first node (lane clamped to written slots)
    int d0  = sdeg[wv];
    int idn = nbrf[(size_t)min(node0 + wv, N_NODES - 1) * CAP + min(lane, max(d0, 1) - 1)];

    for (int nn = 0; nn < 4; ++nn) {
        int li   = nn * 4 + wv;
        int node = node0 + li;
        int deg  = sdeg[li];
        int id   = idn;                       // ids for this node

        // prefetch next node's ids while this node's rows load/decode
        if (nn < 3) {
            int lin = li + 4;
            int dn  = sdeg[lin];
            idn = nbrf[(size_t)min(node0 + lin, N_NODES - 1) * CAP + min(lane, max(dn, 1) - 1)];
        }

        if (node < N_NODES) {                    // wave-uniform
            // hoisted hv read: overlaps with the gather latency below
            float2 v = make_float2(0.f, 0.f);
            if (half == 0)
                v = ((const float2*)hv)[(size_t)node * 32 + m];

            float p0=0,p1=0,p2=0,p3=0,q0=0,q1=0,q2=0,q3=0;
            for (int r = 0; r < deg; r += 16) {   // wave-uniform trips; deg<=64
#pragma unroll
                for (int i = 0; i < 8; ++i) {
                    int e   = r + 2 * i + half;   // < 64 always
                    int ide = __shfl(id, e);      // id from registers
                    unsigned int w = u16[(size_t)ide * 32 + m];
                    w = (e < deg) ? w : 0u;       // mask packed word
                    v2f d = fp8x2<false>(w);      // 1 HW instruction
                    if ((i & 3) == 0)      { p0 += d.x; q0 += d.y; }
                    else if ((i & 3) == 1) { p1 += d.x; q1 += d.y; }
                    else if ((i & 3) == 2) { p2 += d.x; q2 += d.y; }
                    else                   { p3 += d.x; q3 += d.y; }
                }
            }
            float P = (p0 + p1) + (p2 + p3);
            float Q = (q0 + q1) + (q2 + q3);
            P += __shfl_xor(P, 32);    // combine the two half-waves
            Q += __shfl_xor(Q, 32);
            if (half == 0) {
                float inv = 1.0f / (float)max(deg, 1);
                float h0 = P * inv + v.x;
                float h1 = Q * inv + v.y;
                ((float2*)hv)[(size_t)node * 32 + m] = make_float2(h0, h1);
                s1_0 += h0; s1_1 += h1;
                s2_0 += h0 * h0; s2_1 += h1 * h1;
            }
        }
    }

    __shared__ float2 redA[256];
    __shared__ float2 redB[256];
    redA[threadIdx.x] = make_float2(s1_0, s1_1);
    redB[threadIdx.x] = make_float2(s2_0, s2_1);
    __syncthreads();
    if (threadIdx.x < 32) {
        int mm = threadIdx.x;
        float a0=0,a1=0,b0=0,b1=0;
        for (int w = 0; w < 4; ++w) {
            float2 A = redA[w * 64 + mm]; a0 += A.x; a1 += A.y;
            float2 B = redB[w * 64 + mm]; b0 += B.x; b1 += B.y;
        }
        atomicAdd(&sums[2 * mm], a0);  atomicAdd(&sums[2 * mm + 1], a1);
        atomicAdd(&sumsq[2 * mm], b0); atomicAdd(&sumsq[2 * mm + 1], b1);
    }
}

// ===========================================================================
// dense2_bn (R8 proven, plain hv layout): BN finalize + BN+ReLU fused.
// ===========================================================================
__global__ __launch_bounds__(256) void dense2_bn_kernel(
    const float* __restrict__ h, const float* __restrict__ sums,
    const float* __restrict__ sumsq, const float* __restrict__ gamma,
    const float* __restrict__ beta, const float* __restrict__ W2l,
    const float* __restrict__ W2r, const float* __restrict__ b2,
    unsigned char* __restrict__ t40, float* __restrict__ out)
{
    __shared__ float wlT[64 * 65];
    __shared__ float wrT[64 * 65];
    for (int idx = threadIdx.x; idx < 2560; idx += 256) {
        int f = idx >> 6, k = idx & 63;      // f < 40
        wlT[k * 65 + f] = W2l[idx];
        wrT[k * 65 + f] = W2r[idx];
    }
    __syncthreads();

    int f  = threadIdx.x & 63;
    int wv = threadIdx.x >> 6;
    int fc = (f < 40) ? f : 39;
    float wl[64], wr[64];
#pragma unroll
    for (int k = 0; k < 64; ++k) {
        wl[k] = wlT[k * 65 + fc];
        wr[k] = wrT[k * 65 + fc];
    }
    float bias = b2[fc];

    // BN finalize (redundant per block, ~10 insts)
    float inv_n = 1.0f / (float)N_NODES;
    float mu  = sums[f] * inv_n;
    float var = sumsq[f] * inv_n - mu * mu;
    float rs  = rsqrtf(var + BN_EPS);
    float sc  = gamma[f] * rs;
    float sh  = beta[f] - mu * sc;

    int node0 = blockIdx.x * 64;

    for (int nn = 0; nn < 16; ++nn) {
        int node = node0 + nn * 4 + wv;          // wave-uniform
        if (node < N_NODES) {
            float hvv = h[(size_t)node * 64 + f];
            float hn  = fmaxf(hvv * sc + sh, 0.f);   // BN + ReLU fused
            float ta = 0.f, ra = bias;
#pragma unroll
            for (int k = 0; k < 64; ++k) {
                float hb = bcast(hn, k);
                ta += hb * wl[k];
                ra += hb * wr[k];
            }
            if (f < 40) {
                t40[(size_t)node * 64 + f] = f2fp8(ta);
                out[(size_t)node * 40 + f] = ra;
            }
        }
    }
}

// ===========================================================================
// gather2 v11 (R24): v10 pipelined inner structure unchanged; 16 nodes/block
// (grid 6250) for the same waves-x-inflight reason as gather1 v14.
// ===========================================================================
__global__ __launch_bounds__(256) void gather2_kernel(
    const unsigned int* __restrict__ t40, const int* __restrict__ cnt,
    const int* __restrict__ nbrf, float* __restrict__ out)
{
    __shared__ int sdeg[16];
    int node0 = blockIdx.x * 16;
    if (threadIdx.x < 16) {
        int n = node0 + threadIdx.x;
        sdeg[threadIdx.x] = (n < N_NODES) ? min(cnt[n], CAP) : 0;
    }
    __syncthreads();

    int lane = threadIdx.x & 63;
    int q    = lane >> 4;          // quarter 0..3
    int m    = lane & 15;          // dword in row; cl<10 used
    int cl   = (m < 10) ? m : 9;
    int wv   = threadIdx.x >> 6;

    int dA = sdeg[wv], dB = sdeg[wv + 4];
    int idA = nbrf[(size_t)min(node0 + wv,     N_NODES - 1) * CAP + min(lane, max(dA, 1) - 1)];
    int idB = nbrf[(size_t)min(node0 + wv + 4, N_NODES - 1) * CAP + min(lane, max(dB, 1) - 1)];

    unsigned int r0A[4], r1A[4], r0B[4], r1B[4];
    {
        int cnt0 = dA;
#pragma unroll
        for (int i = 0; i < 4; ++i) {
            int e   = 4 * i + q;
            int ide = __shfl(idA, max(min(e, cnt0 - 1), 0));
            r0A[i] = t40[(size_t)ide * 16 + cl];
        }
        if (cnt0 > 16) {
#pragma unroll
            for (int i = 0; i < 4; ++i) {
                int e   = 16 + 4 * i + q;
                int ide = __shfl(idA, min(e, cnt0 - 1));
                r1A[i] = t40[(size_t)ide * 16 + cl];
            }
        }
    }

    for (int nn = 0; nn < 4; ++nn) {
        int li   = nn * 4 + wv;
        int node = node0 + li;
        int deg  = sdeg[li];

        int idC = 0;
        if (nn < 2) {
            int lic = li + 8;
            int dc  = sdeg[lic];
            idC = nbrf[(size_t)min(node0 + lic, N_NODES - 1) * CAP + min(lane, max(dc, 1) - 1)];
        }
        if (nn < 3) {
            int cntn = sdeg[li + 4];
#pragma unroll
            for (int i = 0; i < 4; ++i) {
                int e   = 4 * i + q;
                int ide = __shfl(idB, max(min(e, cntn - 1), 0));
                r0B[i] = t40[(size_t)ide * 16 + cl];
            }
            if (cntn > 16) {
#pragma unroll
                for (int i = 0; i < 4; ++i) {
                    int e   = 16 + 4 * i + q;
                    int ide = __shfl(idB, min(e, cntn - 1));
                    r1B[i] = t40[(size_t)ide * 16 + cl];
                }
            }
        }

        if (node < N_NODES) {                    // wave-uniform
            float4 o = make_float4(0.f, 0.f, 0.f, 0.f);
            if (lane < 10)
                o = ((const float4*)out)[(size_t)node * 10 + m];

            float a0=0,a1=0,a2=0,a3=0, b0=0,b1=0,b2=0,b3=0;
            // round 0 from prefetched regs
#pragma unroll
            for (int i = 0; i < 4; ++i) {
                int e = 4 * i + q;
                unsigned int w = (e < deg) ? r0A[i] : 0u;
                v2f dlo = fp8x2<false>(w);
                v2f dhi = fp8x2<true>(w);
                if (i & 1) { b0 += dlo.x; b1 += dlo.y; b2 += dhi.x; b3 += dhi.y; }
                else       { a0 += dlo.x; a1 += dlo.y; a2 += dhi.x; a3 += dhi.y; }
            }
            if (deg > 16) {                      // wave-uniform
#pragma unroll
                for (int i = 0; i < 4; ++i) {
                    int e = 16 + 4 * i + q;
                    unsigned int w = (e < deg) ? r1A[i] : 0u;
                    v2f dlo = fp8x2<false>(w);
                    v2f dhi = fp8x2<true>(w);
                    if (i & 1) { b0 += dlo.x; b1 += dlo.y; b2 += dhi.x; b3 += dhi.y; }
                    else       { a0 += dlo.x; a1 += dlo.y; a2 += dhi.x; a3 += dhi.y; }
                }
                for (int r = 32; r < deg; r += 16) {
#pragma unroll
                    for (int i = 0; i < 4; ++i) {
                        int e   = r + 4 * i + q;
                        int ide = __shfl(idA, min(e, deg - 1));
                        unsigned int w = t40[(size_t)ide * 16 + cl];
                        w = (e < deg) ? w : 0u;
                        v2f dlo = fp8x2<false>(w);
                        v2f dhi = fp8x2<true>(w);
                        if (i & 1) { b0 += dlo.x; b1 += dlo.y; b2 += dhi.x; b3 += dhi.y; }
                        else       { a0 += dlo.x; a1 += dlo.y; a2 += dhi.x; a3 += dhi.y; }
                    }
                }
            }
            a0 += b0; a1 += b1; a2 += b2; a3 += b3;
            a0 += __shfl_xor(a0, 16); a0 += __shfl_xor(a0, 32);
            a1 += __shfl_xor(a1, 16); a1 += __shfl_xor(a1, 32);
            a2 += __shfl_xor(a2, 16); a2 += __shfl_xor(a2, 32);
            a3 += __shfl_xor(a3, 16); a3 += __shfl_xor(a3, 32);
            if (lane < 10) {
                float inv = 1.0f / (float)max(deg, 1);
                o.x += a0 * inv;
                o.y += a1 * inv;
                o.z += a2 * inv;
                o.w += a3 * inv;
                ((float4*)out)[(size_t)node * 10 + m] = o;
            }
        }

        idA = idB; idB = idC;
#pragma unroll
        for (int i = 0; i < 4; ++i) { r0A[i] = r0B[i]; r1A[i] = r1B[i]; }
    }
}

extern "C" void kernel_launch(void* const* d_in, const int* in_sizes, int n_in,
                              void* d_out, int out_size, void* d_ws, size_t ws_size,
                              hipStream_t stream)
{
    const float* x     = (const float*)d_in[0];
    const int*   ei    = (const int*)d_in[1];
    const float* W1l   = (const float*)d_in[2];
    const float* W1r   = (const float*)d_in[3];
    const float* b1    = (const float*)d_in[4];
    const float* gamma = (const float*)d_in[5];
    const float* beta  = (const float*)d_in[6];
    const float* W2l   = (const float*)d_in[7];
    const float* W2r   = (const float*)d_in[8];
    const float* b2    = (const float*)d_in[9];
    float* out = (float*)d_out;

    const int4* src4 = (const int4*)ei;              // edge_index[0], 16B-aligned
    const int4* dst4 = (const int4*)(ei + N_EDGES);  // edge_index[1]

    // workspace layout (58.0 MB of 58.8), 64B-aligned arrays:
    // hv[N*64] f32 | sums 64 | sumsq 64 | pad 128 | bcur 392 | cnt[N] |
    // nbrf[N*64] int | u8/t40[N*64] fp8.
    // binbuf (7.2 MB) lives in d_out -- scratch until dense2 writes out.
    float* ws    = (float*)d_ws;
    float* hv    = ws;                               // 25.6 MB
    float* sums  = hv + (size_t)N_NODES * 64;        // 64
    float* sumsq = sums + 64;                        // 64
    float* padf  = sumsq + 64;                       // 128 pad
    int* bcur = (int*)(padf + 128);                  // 392 (391 used)
    int* cnt  = bcur + 392;                          // N
    int* nbrf = cnt + N_NODES;                       // N*64 (25.6 MB)
    unsigned char* u8 = (unsigned char*)(nbrf + (size_t)N_NODES * 64);  // 6.4 MB
    unsigned char* t40 = u8;
    unsigned int* binbuf = (unsigned int*)d_out;     // 391*4608*4 = 7.2 MB

    dim3 blk(256);

    // zero sums|sumsq|pad|bcur only (cnt written exactly by binB): 2592 B
    (void)hipMemsetAsync(sums, 0, (size_t)(64 + 64 + 128 + 392) * 4, stream);

    int dblocks = (N_NODES + 63) / 64;

    // ---- edge radix partition (391 coarse bins) ----
    binA_kernel<<<391, 1024, 0, stream>>>(src4, dst4, bcur, binbuf);

    // ---- per-bin bucket build (LDS atomics) + layer-1 dense, FUSED ----
    binB_dense1_kernel<<<NBINS + D1_BLOCKS, blk, 0, stream>>>(
        binbuf, bcur, cnt, nbrf, x, W1l, W1r, b1, u8, hv);

    // ---- layer-1 gather: 16 nodes/block, grid 6250 (occupancy-driven) ----
    gather1_bn_kernel<<<G_BLOCKS, blk, 0, stream>>>(
        (const unsigned short*)u8, cnt, nbrf, hv, sums, sumsq);

    // ---- layer 2 (BN finalize + BN+ReLU fused into dense2) ----
    dense2_bn_kernel<<<dblocks, blk, 0, stream>>>(
        hv, sums, sumsq, gamma, beta, W2l, W2r, b2, t40, out);
    gather2_kernel<<<G_BLOCKS, blk, 0, stream>>>(
        (const unsigned int*)t40, cnt, nbrf, out);
}

// Round 11
// 286.949 us; speedup vs baseline: 2.0841x; 1.9439x over previous
//
#include <hip/hip_runtime.h>
#include <hip/hip_fp8.h>

#define N_NODES 100000
#define N_EDGES 1600000
#define BN_EPS 1e-5f
#define E4 400000        // N_EDGES / 4 (int4 count)
#define D1_BLOCKS 1563   // ceil(100000/64)
#define CAP 64           // bucket capacity; P(deg>64) ~ 1e-20/node (Poisson 16)
#define NBINS 391        // bins of 256 nodes: bin = dst >> 8 (max 99999>>8 = 390)
#define BINCAP 4608      // mean 4096 + 8 sigma
#define BIN_MASK 255
#define G_BLOCKS 6250    // gathers: 16 nodes/block (exact: 6250*16 = 100000)
#define NCOPY 32         // replicated BN-stat accumulators (contention /32)

typedef float v2f __attribute__((ext_vector_type(2)));

// broadcast lane k's value (readlane). Wave-uniform control flow ONLY.
__device__ __forceinline__ float bcast(float v, int k) {
    return __uint_as_float(__builtin_amdgcn_readlane(__float_as_uint(v), k));
}
// fp8 e4m3 encode (cold path: once per element in the dense kernels)
__device__ __forceinline__ unsigned char f2fp8(float x) {
    return (unsigned char)__hip_cvt_float_to_fp8(x, __HIP_SATFINITE, __HIP_E4M3);
}
// HW packed decode: 2 x fp8(e4m3) -> 2 x f32 in ONE VALU instruction.
template <bool HI>
__device__ __forceinline__ v2f fp8x2(unsigned int w) {
#if __has_builtin(__builtin_amdgcn_cvt_pk_f32_fp8)
    return __builtin_amdgcn_cvt_pk_f32_fp8((int)w, HI);
#else
    unsigned int b = HI ? (w >> 16) : w;
    __half_raw h0 = __hip_cvt_fp8_to_halfraw((__hip_fp8_storage_t)(b & 0xFF), __HIP_E4M3);
    __half_raw h1 = __hip_cvt_fp8_to_halfraw((__hip_fp8_storage_t)((b >> 8) & 0xFF), __HIP_E4M3);
    v2f r; r.x = __half2float(__half(h0)); r.y = __half2float(__half(h1));
    return r;
#endif
}

// ===========================================================================
// binA (R22 proven): radix partition into 391 coarse bins; LDS counting +
// one bulk global claim per bin per block. binbuf lives in d_out.
// ===========================================================================
__global__ __launch_bounds__(1024) void binA_kernel(
    const int4* __restrict__ src4, const int4* __restrict__ dst4,
    int* __restrict__ bcur, unsigned int* __restrict__ binbuf)
{
    __shared__ int lcnt[NBINS];
    __shared__ int lbase[NBINS];
    int tid = threadIdx.x;
    if (tid < NBINS) lcnt[tid] = 0;
    __syncthreads();

    int i = blockIdx.x * 1024 + tid;
    int4 d, s;
    int b0 = 0, b1 = 0, b2 = 0, b3 = 0, r0 = 0, r1 = 0, r2 = 0, r3 = 0;
    bool valid = (i < E4);
    if (valid) {
        d = dst4[i]; s = src4[i];
        b0 = d.x >> 8; r0 = atomicAdd(&lcnt[b0], 1);
        b1 = d.y >> 8; r1 = atomicAdd(&lcnt[b1], 1);
        b2 = d.z >> 8; r2 = atomicAdd(&lcnt[b2], 1);
        b3 = d.w >> 8; r3 = atomicAdd(&lcnt[b3], 1);
    }
    __syncthreads();
    if (tid < NBINS && lcnt[tid] > 0)
        lbase[tid] = atomicAdd(&bcur[tid], lcnt[tid]);
    __syncthreads();
    if (valid) {
        int p;
        p = lbase[b0] + r0; if (p < BINCAP) binbuf[(size_t)b0 * BINCAP + p] = ((unsigned)s.x << 8) | (unsigned)(d.x & BIN_MASK);
        p = lbase[b1] + r1; if (p < BINCAP) binbuf[(size_t)b1 * BINCAP + p] = ((unsigned)s.y << 8) | (unsigned)(d.y & BIN_MASK);
        p = lbase[b2] + r2; if (p < BINCAP) binbuf[(size_t)b2 * BINCAP + p] = ((unsigned)s.z << 8) | (unsigned)(d.z & BIN_MASK);
        p = lbase[b3] + r3; if (p < BINCAP) binbuf[(size_t)b3 * BINCAP + p] = ((unsigned)s.w << 8) | (unsigned)(d.w & BIN_MASK);
    }
}

// ===========================================================================
// binB + dense1 FUSED (R22 proven). Plain u8/hv layouts.
// ===========================================================================
__global__ __launch_bounds__(256) void binB_dense1_kernel(
    const unsigned int* __restrict__ binbuf, const int* __restrict__ bcur,
    int* __restrict__ cnt, int* __restrict__ nbrf,
    const float* __restrict__ x, const float* __restrict__ W1l,
    const float* __restrict__ W1r, const float* __restrict__ b1,
    unsigned char* __restrict__ u8, float* __restrict__ hv)
{
    __shared__ float wlT[64 * 65];
    __shared__ float wrT[64 * 65];

    if (blockIdx.x < NBINS) {
        // ---- binB role: per-bin bucket build with LDS slot counters ----
        __shared__ int lc[256];
        int tid = threadIdx.x;
        lc[tid] = 0;
        __syncthreads();
        int bin = blockIdx.x;
        int n = min(bcur[bin], BINCAP);
        for (int i = tid; i < n; i += 256) {
            unsigned int e = binbuf[(size_t)bin * BINCAP + i];
            int dl  = (int)(e & BIN_MASK);
            int src = (int)(e >> 8);
            int slot = atomicAdd(&lc[dl], 1);          // LDS atomic
            if (slot < CAP)
                nbrf[((size_t)(bin * 256 + dl)) * CAP + slot] = src;
        }
        __syncthreads();
        int node = bin * 256 + tid;
        if (node < N_NODES) {
            int c = min(lc[tid], CAP);
            cnt[node] = c;
            if (c == 0) nbrf[(size_t)node * CAP] = 0;  // safe id for deg==0
        }
        return;
    }

    // ---- dense1 role ----
    for (int idx = threadIdx.x; idx < 4096; idx += 256) {
        int f = idx >> 6, k = idx & 63;
        wlT[k * 65 + f] = W1l[idx];
        wrT[k * 65 + f] = W1r[idx];
    }
    __syncthreads();

    int f  = threadIdx.x & 63;
    int wv = threadIdx.x >> 6;
    float wl[64], wr[64];
#pragma unroll
    for (int k = 0; k < 64; ++k) {
        wl[k] = wlT[k * 65 + f];
        wr[k] = wrT[k * 65 + f];
    }
    float bias = b1[f];
    int node0 = (blockIdx.x - NBINS) * 64;

    for (int nn = 0; nn < 16; ++nn) {
        int node = node0 + nn * 4 + wv;          // wave-uniform
        if (node < N_NODES) {
            float xv = x[(size_t)node * 64 + f];
            float ua = 0.f, va = bias;
#pragma unroll
            for (int k = 0; k < 64; ++k) {
                float xb = bcast(xv, k);
                ua += xb * wl[k];
                va += xb * wr[k];
            }
            u8[(size_t)node * 64 + f] = f2fp8(ua);   // coalesced 64B/node
            hv[(size_t)node * 64 + f] = va;
        }
    }
}

// ===========================================================================
// gather1_bn v15 (R25): v14's 16-node/block occupancy structure (R10) with
// the BN-stats epilogue DE-CONTENDED: atomics go to sumsR[blockIdx&31][128]
// (32 replicated copies). R10's diagnosis: 800K device atomics onto the SAME
// 8 cache lines serialized at the memory-side coherence point (~330us,
// matching the measured 311); VALU time was unchanged. Contention /32 ->
// ~10us, pipelined. Inner gather byte-identical to v12/v14.
// ===========================================================================
__global__ __launch_bounds__(256) void gather1_bn_kernel(
    const unsigned short* __restrict__ u16, const int* __restrict__ cnt,
    const int* __restrict__ nbrf, float* __restrict__ hv,
    float* __restrict__ sumsR)
{
    __shared__ int sdeg[16];
    int node0 = blockIdx.x * 16;
    if (threadIdx.x < 16) {
        int n = node0 + threadIdx.x;
        sdeg[threadIdx.x] = (n < N_NODES) ? min(cnt[n], CAP) : 0;
    }
    __syncthreads();

    int lane = threadIdx.x & 63;
    int m    = lane & 31;
    int half = lane >> 5;
    int wv   = threadIdx.x >> 6;
    float s1_0 = 0.f, s1_1 = 0.f, s2_0 = 0.f, s2_1 = 0.f;

    // prefetch ids for the first node (lane clamped to written slots)
    int d0  = sdeg[wv];
    int idn = nbrf[(size_t)min(node0 + wv, N_NODES - 1) * CAP + min(lane, max(d0, 1) - 1)];

    for (int nn = 0; nn < 4; ++nn) {
        int li   = nn * 4 + wv;
        int node = node0 + li;
        int deg  = sdeg[li];
        int id   = idn;                       // ids for this node

        // prefetch next node's ids while this node's rows load/decode
        if (nn < 3) {
            int lin = li + 4;
            int dn  = sdeg[lin];
            idn = nbrf[(size_t)min(node0 + lin, N_NODES - 1) * CAP + min(lane, max(dn, 1) - 1)];
        }

        if (node < N_NODES) {                    // wave-uniform
            // hoisted hv read: overlaps with the gather latency below
            float2 v = make_float2(0.f, 0.f);
            if (half == 0)
                v = ((const float2*)hv)[(size_t)node * 32 + m];

            float p0=0,p1=0,p2=0,p3=0,q0=0,q1=0,q2=0,q3=0;
            for (int r = 0; r < deg; r += 16) {   // wave-uniform trips; deg<=64
#pragma unroll
                for (int i = 0; i < 8; ++i) {
                    int e   = r + 2 * i + half;   // < 64 always
                    int ide = __shfl(id, e);      // id from registers
                    unsigned int w = u16[(size_t)ide * 32 + m];
                    w = (e < deg) ? w : 0u;       // mask packed word
                    v2f d = fp8x2<false>(w);      // 1 HW instruction
                    if ((i & 3) == 0)      { p0 += d.x; q0 += d.y; }
                    else if ((i & 3) == 1) { p1 += d.x; q1 += d.y; }
                    else if ((i & 3) == 2) { p2 += d.x; q2 += d.y; }
                    else                   { p3 += d.x; q3 += d.y; }
                }
            }
            float P = (p0 + p1) + (p2 + p3);
            float Q = (q0 + q1) + (q2 + q3);
            P += __shfl_xor(P, 32);    // combine the two half-waves
            Q += __shfl_xor(Q, 32);
            if (half == 0) {
                float inv = 1.0f / (float)max(deg, 1);
                float h0 = P * inv + v.x;
                float h1 = Q * inv + v.y;
                ((float2*)hv)[(size_t)node * 32 + m] = make_float2(h0, h1);
                s1_0 += h0; s1_1 += h1;
                s2_0 += h0 * h0; s2_1 += h1 * h1;
            }
        }
    }

    __shared__ float2 redA[256];
    __shared__ float2 redB[256];
    redA[threadIdx.x] = make_float2(s1_0, s1_1);
    redB[threadIdx.x] = make_float2(s2_0, s2_1);
    __syncthreads();
    if (threadIdx.x < 32) {
        int mm = threadIdx.x;
        float a0=0,a1=0,b0=0,b1=0;
        for (int w = 0; w < 4; ++w) {
            float2 A = redA[w * 64 + mm]; a0 += A.x; a1 += A.y;
            float2 B = redB[w * 64 + mm]; b0 += B.x; b1 += B.y;
        }
        float* base = sumsR + (size_t)(blockIdx.x & (NCOPY - 1)) * 128;
        atomicAdd(&base[2 * mm], a0);       atomicAdd(&base[2 * mm + 1], a1);
        atomicAdd(&base[64 + 2 * mm], b0);  atomicAdd(&base[64 + 2 * mm + 1], b1);
    }
}

// ===========================================================================
// dense2_bn (R25): BN finalize now sums the 32 replicated stat copies
// (16KB, L2-resident, 64 loads/thread amortized once per block).
// ===========================================================================
__global__ __launch_bounds__(256) void dense2_bn_kernel(
    const float* __restrict__ h, const float* __restrict__ sumsR,
    const float* __restrict__ gamma, const float* __restrict__ beta,
    const float* __restrict__ W2l, const float* __restrict__ W2r,
    const float* __restrict__ b2,
    unsigned char* __restrict__ t40, float* __restrict__ out)
{
    __shared__ float wlT[64 * 65];
    __shared__ float wrT[64 * 65];
    for (int idx = threadIdx.x; idx < 2560; idx += 256) {
        int f = idx >> 6, k = idx & 63;      // f < 40
        wlT[k * 65 + f] = W2l[idx];
        wrT[k * 65 + f] = W2r[idx];
    }
    __syncthreads();

    int f  = threadIdx.x & 63;
    int wv = threadIdx.x >> 6;
    int fc = (f < 40) ? f : 39;
    float wl[64], wr[64];
#pragma unroll
    for (int k = 0; k < 64; ++k) {
        wl[k] = wlT[k * 65 + fc];
        wr[k] = wrT[k * 65 + fc];
    }
    float bias = b2[fc];

    // BN finalize: reduce 32 replicated copies, then normalize constants
    float s = 0.f, q = 0.f;
#pragma unroll
    for (int c = 0; c < NCOPY; ++c) {
        s += sumsR[c * 128 + f];
        q += sumsR[c * 128 + 64 + f];
    }
    float inv_n = 1.0f / (float)N_NODES;
    float mu  = s * inv_n;
    float var = q * inv_n - mu * mu;
    float rs  = rsqrtf(var + BN_EPS);
    float sc  = gamma[f] * rs;
    float sh  = beta[f] - mu * sc;

    int node0 = blockIdx.x * 64;

    for (int nn = 0; nn < 16; ++nn) {
        int node = node0 + nn * 4 + wv;          // wave-uniform
        if (node < N_NODES) {
            float hvv = h[(size_t)node * 64 + f];
            float hn  = fmaxf(hvv * sc + sh, 0.f);   // BN + ReLU fused
            float ta = 0.f, ra = bias;
#pragma unroll
            for (int k = 0; k < 64; ++k) {
                float hb = bcast(hn, k);
                ta += hb * wl[k];
                ra += hb * wr[k];
            }
            if (f < 40) {
                t40[(size_t)node * 64 + f] = f2fp8(ta);
                out[(size_t)node * 40 + f] = ra;
            }
        }
    }
}

// ===========================================================================
// gather2 v11 (R24, kept: improved ~15us vs 64-node blocks by total-time
// decomposition): v10 pipelined inner structure; 16 nodes/block, grid 6250.
// ===========================================================================
__global__ __launch_bounds__(256) void gather2_kernel(
    const unsigned int* __restrict__ t40, const int* __restrict__ cnt,
    const int* __restrict__ nbrf, float* __restrict__ out)
{
    __shared__ int sdeg[16];
    int node0 = blockIdx.x * 16;
    if (threadIdx.x < 16) {
        int n = node0 + threadIdx.x;
        sdeg[threadIdx.x] = (n < N_NODES) ? min(cnt[n], CAP) : 0;
    }
    __syncthreads();

    int lane = threadIdx.x & 63;
    int q    = lane >> 4;          // quarter 0..3
    int m    = lane & 15;          // dword in row; cl<10 used
    int cl   = (m < 10) ? m : 9;
    int wv   = threadIdx.x >> 6;

    int dA = sdeg[wv], dB = sdeg[wv + 4];
    int idA = nbrf[(size_t)min(node0 + wv,     N_NODES - 1) * CAP + min(lane, max(dA, 1) - 1)];
    int idB = nbrf[(size_t)min(node0 + wv + 4, N_NODES - 1) * CAP + min(lane, max(dB, 1) - 1)];

    unsigned int r0A[4], r1A[4], r0B[4], r1B[4];
    {
        int cnt0 = dA;
#pragma unroll
        for (int i = 0; i < 4; ++i) {
            int e   = 4 * i + q;
            int ide = __shfl(idA, max(min(e, cnt0 - 1), 0));
            r0A[i] = t40[(size_t)ide * 16 + cl];
        }
        if (cnt0 > 16) {
#pragma unroll
            for (int i = 0; i < 4; ++i) {
                int e   = 16 + 4 * i + q;
                int ide = __shfl(idA, min(e, cnt0 - 1));
                r1A[i] = t40[(size_t)ide * 16 + cl];
            }
        }
    }

    for (int nn = 0; nn < 4; ++nn) {
        int li   = nn * 4 + wv;
        int node = node0 + li;
        int deg  = sdeg[li];

        int idC = 0;
        if (nn < 2) {
            int lic = li + 8;
            int dc  = sdeg[lic];
            idC = nbrf[(size_t)min(node0 + lic, N_NODES - 1) * CAP + min(lane, max(dc, 1) - 1)];
        }
        if (nn < 3) {
            int cntn = sdeg[li + 4];
#pragma unroll
            for (int i = 0; i < 4; ++i) {
                int e   = 4 * i + q;
                int ide = __shfl(idB, max(min(e, cntn - 1), 0));
                r0B[i] = t40[(size_t)ide * 16 + cl];
            }
            if (cntn > 16) {
#pragma unroll
                for (int i = 0; i < 4; ++i) {
                    int e   = 16 + 4 * i + q;
                    int ide = __shfl(idB, min(e, cntn - 1));
                    r1B[i] = t40[(size_t)ide * 16 + cl];
                }
            }
        }

        if (node < N_NODES) {                    // wave-uniform
            float4 o = make_float4(0.f, 0.f, 0.f, 0.f);
            if (lane < 10)
                o = ((const float4*)out)[(size_t)node * 10 + m];

            float a0=0,a1=0,a2=0,a3=0, b0=0,b1=0,b2=0,b3=0;
            // round 0 from prefetched regs
#pragma unroll
            for (int i = 0; i < 4; ++i) {
                int e = 4 * i + q;
                unsigned int w = (e < deg) ? r0A[i] : 0u;
                v2f dlo = fp8x2<false>(w);
                v2f dhi = fp8x2<true>(w);
                if (i & 1) { b0 += dlo.x; b1 += dlo.y; b2 += dhi.x; b3 += dhi.y; }
                else       { a0 += dlo.x; a1 += dlo.y; a2 += dhi.x; a3 += dhi.y; }
            }
            if (deg > 16) {                      // wave-uniform
#pragma unroll
                for (int i = 0; i < 4; ++i) {
                    int e = 16 + 4 * i + q;
                    unsigned int w = (e < deg) ? r1A[i] : 0u;
                    v2f dlo = fp8x2<false>(w);
                    v2f dhi = fp8x2<true>(w);
                    if (i & 1) { b0 += dlo.x; b1 += dlo.y; b2 += dhi.x; b3 += dhi.y; }
                    else       { a0 += dlo.x; a1 += dlo.y; a2 += dhi.x; a3 += dhi.y; }
                }
                for (int r = 32; r < deg; r += 16) {
#pragma unroll
                    for (int i = 0; i < 4; ++i) {
                        int e   = r + 4 * i + q;
                        int ide = __shfl(idA, min(e, deg - 1));
                        unsigned int w = t40[(size_t)ide * 16 + cl];
                        w = (e < deg) ? w : 0u;
                        v2f dlo = fp8x2<false>(w);
                        v2f dhi = fp8x2<true>(w);
                        if (i & 1) { b0 += dlo.x; b1 += dlo.y; b2 += dhi.x; b3 += dhi.y; }
                        else       { a0 += dlo.x; a1 += dlo.y; a2 += dhi.x; a3 += dhi.y; }
                    }
                }
            }
            a0 += b0; a1 += b1; a2 += b2; a3 += b3;
            a0 += __shfl_xor(a0, 16); a0 += __shfl_xor(a0, 32);
            a1 += __shfl_xor(a1, 16); a1 += __shfl_xor(a1, 32);
            a2 += __shfl_xor(a2, 16); a2 += __shfl_xor(a2, 32);
            a3 += __shfl_xor(a3, 16); a3 += __shfl_xor(a3, 32);
            if (lane < 10) {
                float inv = 1.0f / (float)max(deg, 1);
                o.x += a0 * inv;
                o.y += a1 * inv;
                o.z += a2 * inv;
                o.w += a3 * inv;
                ((float4*)out)[(size_t)node * 10 + m] = o;
            }
        }

        idA = idB; idB = idC;
#pragma unroll
        for (int i = 0; i < 4; ++i) { r0A[i] = r0B[i]; r1A[i] = r1B[i]; }
    }
}

extern "C" void kernel_launch(void* const* d_in, const int* in_sizes, int n_in,
                              void* d_out, int out_size, void* d_ws, size_t ws_size,
                              hipStream_t stream)
{
    const float* x     = (const float*)d_in[0];
    const int*   ei    = (const int*)d_in[1];
    const float* W1l   = (const float*)d_in[2];
    const float* W1r   = (const float*)d_in[3];
    const float* b1    = (const float*)d_in[4];
    const float* gamma = (const float*)d_in[5];
    const float* beta  = (const float*)d_in[6];
    const float* W2l   = (const float*)d_in[7];
    const float* W2r   = (const float*)d_in[8];
    const float* b2    = (const float*)d_in[9];
    float* out = (float*)d_out;

    const int4* src4 = (const int4*)ei;              // edge_index[0], 16B-aligned
    const int4* dst4 = (const int4*)(ei + N_EDGES);  // edge_index[1]

    // workspace layout (58.0 MB of 58.8), 64B-aligned arrays:
    // hv[N*64] f32 | sumsR[32][128] f32 (16KB) | bcur 392 | cnt[N] |
    // nbrf[N*64] int | u8/t40[N*64] fp8.
    // binbuf (7.2 MB) lives in d_out -- scratch until dense2 writes out.
    float* ws    = (float*)d_ws;
    float* hv    = ws;                               // 25.6 MB
    float* sumsR = hv + (size_t)N_NODES * 64;        // 32*128 floats
    int* bcur = (int*)(sumsR + NCOPY * 128);         // 392 (391 used)
    int* cnt  = bcur + 392;                          // N
    int* nbrf = cnt + N_NODES;                       // N*64 (25.6 MB)
    unsigned char* u8 = (unsigned char*)(nbrf + (size_t)N_NODES * 64);  // 6.4 MB
    unsigned char* t40 = u8;
    unsigned int* binbuf = (unsigned int*)d_out;     // 391*4608*4 = 7.2 MB

    dim3 blk(256);

    // zero sumsR | bcur (cnt written exactly by binB): (4096+392)*4 B
    (void)hipMemsetAsync(sumsR, 0, (size_t)(NCOPY * 128 + 392) * 4, stream);

    int dblocks = (N_NODES + 63) / 64;

    // ---- edge radix partition (391 coarse bins) ----
    binA_kernel<<<391, 1024, 0, stream>>>(src4, dst4, bcur, binbuf);

    // ---- per-bin bucket build (LDS atomics) + layer-1 dense, FUSED ----
    binB_dense1_kernel<<<NBINS + D1_BLOCKS, blk, 0, stream>>>(
        binbuf, bcur, cnt, nbrf, x, W1l, W1r, b1, u8, hv);

    // ---- layer-1 gather: 16 nodes/block, grid 6250; de-contended stats ----
    gather1_bn_kernel<<<G_BLOCKS, blk, 0, stream>>>(
        (const unsigned short*)u8, cnt, nbrf, hv, sumsR);

    // ---- layer 2 (BN finalize from 32 copies + BN+ReLU fused) ----
    dense2_bn_kernel<<<dblocks, blk, 0, stream>>>(
        hv, sumsR, gamma, beta, W2l, W2r, b2, t40, out);
    gather2_kernel<<<G_BLOCKS, blk, 0, stream>>>(
        (const unsigned int*)t40, cnt, nbrf, out);
}

// Round 12
// 264.994 us; speedup vs baseline: 2.2567x; 1.0829x over previous
//
#include <hip/hip_runtime.h>
#include <hip/hip_fp8.h>

#define N_NODES 100000
#define N_EDGES 1600000
#define BN_EPS 1e-5f
#define E4 400000        // N_EDGES / 4 (int4 count)
#define CAP 64           // bucket capacity; P(deg>64) ~ 1e-20/node (Poisson 16)
#define NBINS 391        // bins of 256 nodes: bin = dst >> 8 (max 99999>>8 = 390)
#define BINCAP 4608      // mean 4096 + 8 sigma
#define BIN_MASK 255
#define G_BLOCKS 6250    // gathers: 16 nodes/block (exact: 6250*16 = 100000)
#define NCOPY 32         // replicated BN-stat accumulators (contention /32)
#define D1B 391          // dense1 blocks: 256 nodes each (391*256 = 100096)

typedef float v2f __attribute__((ext_vector_type(2)));
typedef __attribute__((ext_vector_type(8))) short bf16x8;   // 8 bf16 (4 VGPRs)
typedef __attribute__((ext_vector_type(4))) float f32x4;

// broadcast lane k's value (readlane). Wave-uniform control flow ONLY.
__device__ __forceinline__ float bcast(float v, int k) {
    return __uint_as_float(__builtin_amdgcn_readlane(__float_as_uint(v), k));
}
__device__ __forceinline__ unsigned short f2bf(float x) {   // round-nearest-even
    unsigned int u = __float_as_uint(x);
    return (unsigned short)((u + 0x7FFF + ((u >> 16) & 1)) >> 16);
}
__device__ __forceinline__ bf16x8 pack8(float4 a, float4 b) {
    bf16x8 r;
    r[0] = (short)f2bf(a.x); r[1] = (short)f2bf(a.y);
    r[2] = (short)f2bf(a.z); r[3] = (short)f2bf(a.w);
    r[4] = (short)f2bf(b.x); r[5] = (short)f2bf(b.y);
    r[6] = (short)f2bf(b.z); r[7] = (short)f2bf(b.w);
    return r;
}
// fp8 e4m3 encode (cold path: once per element in the dense kernels)
__device__ __forceinline__ unsigned char f2fp8(float x) {
    return (unsigned char)__hip_cvt_float_to_fp8(x, __HIP_SATFINITE, __HIP_E4M3);
}
// HW packed decode: 2 x fp8(e4m3) -> 2 x f32 in ONE VALU instruction.
template <bool HI>
__device__ __forceinline__ v2f fp8x2(unsigned int w) {
#if __has_builtin(__builtin_amdgcn_cvt_pk_f32_fp8)
    return __builtin_amdgcn_cvt_pk_f32_fp8((int)w, HI);
#else
    unsigned int b = HI ? (w >> 16) : w;
    __half_raw h0 = __hip_cvt_fp8_to_halfraw((__hip_fp8_storage_t)(b & 0xFF), __HIP_E4M3);
    __half_raw h1 = __hip_cvt_fp8_to_halfraw((__hip_fp8_storage_t)((b >> 8) & 0xFF), __HIP_E4M3);
    v2f r; r.x = __half2float(__half(h0)); r.y = __half2float(__half(h1));
    return r;
#endif
}

// ===========================================================================
// binA (R22 proven): radix partition into 391 coarse bins; LDS counting +
// one bulk global claim per bin per block. binbuf lives in d_out.
// ===========================================================================
__global__ __launch_bounds__(1024) void binA_kernel(
    const int4* __restrict__ src4, const int4* __restrict__ dst4,
    int* __restrict__ bcur, unsigned int* __restrict__ binbuf)
{
    __shared__ int lcnt[NBINS];
    __shared__ int lbase[NBINS];
    int tid = threadIdx.x;
    if (tid < NBINS) lcnt[tid] = 0;
    __syncthreads();

    int i = blockIdx.x * 1024 + tid;
    int4 d, s;
    int b0 = 0, b1 = 0, b2 = 0, b3 = 0, r0 = 0, r1 = 0, r2 = 0, r3 = 0;
    bool valid = (i < E4);
    if (valid) {
        d = dst4[i]; s = src4[i];
        b0 = d.x >> 8; r0 = atomicAdd(&lcnt[b0], 1);
        b1 = d.y >> 8; r1 = atomicAdd(&lcnt[b1], 1);
        b2 = d.z >> 8; r2 = atomicAdd(&lcnt[b2], 1);
        b3 = d.w >> 8; r3 = atomicAdd(&lcnt[b3], 1);
    }
    __syncthreads();
    if (tid < NBINS && lcnt[tid] > 0)
        lbase[tid] = atomicAdd(&bcur[tid], lcnt[tid]);
    __syncthreads();
    if (valid) {
        int p;
        p = lbase[b0] + r0; if (p < BINCAP) binbuf[(size_t)b0 * BINCAP + p] = ((unsigned)s.x << 8) | (unsigned)(d.x & BIN_MASK);
        p = lbase[b1] + r1; if (p < BINCAP) binbuf[(size_t)b1 * BINCAP + p] = ((unsigned)s.y << 8) | (unsigned)(d.y & BIN_MASK);
        p = lbase[b2] + r2; if (p < BINCAP) binbuf[(size_t)b2 * BINCAP + p] = ((unsigned)s.z << 8) | (unsigned)(d.z & BIN_MASK);
        p = lbase[b3] + r3; if (p < BINCAP) binbuf[(size_t)b3 * BINCAP + p] = ((unsigned)s.w << 8) | (unsigned)(d.w & BIN_MASK);
    }
}

// ===========================================================================
// binB + dense1 FUSED. R26 change: dense1 role now uses bf16 MFMA
// (mfma_f32_16x16x32_bf16) instead of the readlane f32 loop -- R11 counters
// showed the fused kernel VALU-bound (VALUBusy 50%, MfmaUtil 0) with dense1
// costing ~3 VALU insts per 4 FLOP. MFMA: A = x rows (16 nodes x K, bf16
// RNE-packed), B = W rows DIRECTLY (W stored [feat][k] row-major = B^T
// fragment layout, no transpose), C/D: col=lane&15, row=(lane>>4)*4+reg.
// K=64 = 2 mfma per C-tile; accumulate f32. Weight frags preloaded once per
// block; wlT/wrT LDS eliminated (33KB -> 1KB).
// ===========================================================================
__global__ __launch_bounds__(256) void binB_dense1_kernel(
    const unsigned int* __restrict__ binbuf, const int* __restrict__ bcur,
    int* __restrict__ cnt, int* __restrict__ nbrf,
    const float* __restrict__ x, const float* __restrict__ W1l,
    const float* __restrict__ W1r, const float* __restrict__ b1,
    unsigned char* __restrict__ u8, float* __restrict__ hv)
{
    if (blockIdx.x < NBINS) {
        // ---- binB role: per-bin bucket build with LDS slot counters ----
        __shared__ int lc[256];
        int tid = threadIdx.x;
        lc[tid] = 0;
        __syncthreads();
        int bin = blockIdx.x;
        int n = min(bcur[bin], BINCAP);
        for (int i = tid; i < n; i += 256) {
            unsigned int e = binbuf[(size_t)bin * BINCAP + i];
            int dl  = (int)(e & BIN_MASK);
            int src = (int)(e >> 8);
            int slot = atomicAdd(&lc[dl], 1);          // LDS atomic
            if (slot < CAP)
                nbrf[((size_t)(bin * 256 + dl)) * CAP + slot] = src;
        }
        __syncthreads();
        int node = bin * 256 + tid;
        if (node < N_NODES) {
            int c = min(lc[tid], CAP);
            cnt[node] = c;
            if (c == 0) nbrf[(size_t)node * CAP] = 0;  // safe id for deg==0
        }
        return;
    }

    // ---- dense1 role (MFMA) ----
    int lane = threadIdx.x & 63;
    int wv   = threadIdx.x >> 6;
    int lr   = lane & 15;          // A-load row / B col / C col
    int lk   = lane >> 4;          // k-group (8 elements each)

    // preload weight fragments: Bf[mat][ftile][khalf]; W rows are B^T frags
    bf16x8 Bf[2][4][2];
#pragma unroll
    for (int mat = 0; mat < 2; ++mat) {
        const float* W = mat ? W1r : W1l;
#pragma unroll
        for (int ft = 0; ft < 4; ++ft) {
#pragma unroll
            for (int kh = 0; kh < 2; ++kh) {
                const float* p = W + (size_t)(ft * 16 + lr) * 64 + kh * 32 + lk * 8;
                Bf[mat][ft][kh] = pack8(*(const float4*)p, *(const float4*)(p + 4));
            }
        }
    }
    float b1v[4];
#pragma unroll
    for (int ft = 0; ft < 4; ++ft) b1v[ft] = b1[ft * 16 + lr];

    int nb = (blockIdx.x - NBINS) * 256;

    for (int it = 0; it < 4; ++it) {
        int n0 = nb + it * 64 + wv * 16;
        int arow = min(n0 + lr, N_NODES - 1);
        const float* xp = x + (size_t)arow * 64 + lk * 8;
        bf16x8 a0 = pack8(*(const float4*)xp,        *(const float4*)(xp + 4));
        bf16x8 a1 = pack8(*(const float4*)(xp + 32), *(const float4*)(xp + 36));

#pragma unroll
        for (int ft = 0; ft < 4; ++ft) {
            f32x4 Cl = {0.f, 0.f, 0.f, 0.f};
            f32x4 Cr = {0.f, 0.f, 0.f, 0.f};
            Cl = __builtin_amdgcn_mfma_f32_16x16x32_bf16(a0, Bf[0][ft][0], Cl, 0, 0, 0);
            Cl = __builtin_amdgcn_mfma_f32_16x16x32_bf16(a1, Bf[0][ft][1], Cl, 0, 0, 0);
            Cr = __builtin_amdgcn_mfma_f32_16x16x32_bf16(a0, Bf[1][ft][0], Cr, 0, 0, 0);
            Cr = __builtin_amdgcn_mfma_f32_16x16x32_bf16(a1, Bf[1][ft][1], Cr, 0, 0, 0);
#pragma unroll
            for (int r = 0; r < 4; ++r) {
                int node = n0 + lk * 4 + r;
                if (node < N_NODES) {
                    u8[(size_t)node * 64 + ft * 16 + lr] = f2fp8(Cl[r]);
                    hv[(size_t)node * 64 + ft * 16 + lr] = Cr[r] + b1v[ft];
                }
            }
        }
    }
}

// ===========================================================================
// gather1_bn v15 (R25 proven): 16-node/block occupancy structure with
// de-contended BN stats (sumsR[blockIdx&31][128]).
// ===========================================================================
__global__ __launch_bounds__(256) void gather1_bn_kernel(
    const unsigned short* __restrict__ u16, const int* __restrict__ cnt,
    const int* __restrict__ nbrf, float* __restrict__ hv,
    float* __restrict__ sumsR)
{
    __shared__ int sdeg[16];
    int node0 = blockIdx.x * 16;
    if (threadIdx.x < 16) {
        int n = node0 + threadIdx.x;
        sdeg[threadIdx.x] = (n < N_NODES) ? min(cnt[n], CAP) : 0;
    }
    __syncthreads();

    int lane = threadIdx.x & 63;
    int m    = lane & 31;
    int half = lane >> 5;
    int wv   = threadIdx.x >> 6;
    float s1_0 = 0.f, s1_1 = 0.f, s2_0 = 0.f, s2_1 = 0.f;

    // prefetch ids for the first node (lane clamped to written slots)
    int d0  = sdeg[wv];
    int idn = nbrf[(size_t)min(node0 + wv, N_NODES - 1) * CAP + min(lane, max(d0, 1) - 1)];

    for (int nn = 0; nn < 4; ++nn) {
        int li   = nn * 4 + wv;
        int node = node0 + li;
        int deg  = sdeg[li];
        int id   = idn;                       // ids for this node

        // prefetch next node's ids while this node's rows load/decode
        if (nn < 3) {
            int lin = li + 4;
            int dn  = sdeg[lin];
            idn = nbrf[(size_t)min(node0 + lin, N_NODES - 1) * CAP + min(lane, max(dn, 1) - 1)];
        }

        if (node < N_NODES) {                    // wave-uniform
            // hoisted hv read: overlaps with the gather latency below
            float2 v = make_float2(0.f, 0.f);
            if (half == 0)
                v = ((const float2*)hv)[(size_t)node * 32 + m];

            float p0=0,p1=0,p2=0,p3=0,q0=0,q1=0,q2=0,q3=0;
            for (int r = 0; r < deg; r += 16) {   // wave-uniform trips; deg<=64
#pragma unroll
                for (int i = 0; i < 8; ++i) {
                    int e   = r + 2 * i + half;   // < 64 always
                    int ide = __shfl(id, e);      // id from registers
                    unsigned int w = u16[(size_t)ide * 32 + m];
                    w = (e < deg) ? w : 0u;       // mask packed word
                    v2f d = fp8x2<false>(w);      // 1 HW instruction
                    if ((i & 3) == 0)      { p0 += d.x; q0 += d.y; }
                    else if ((i & 3) == 1) { p1 += d.x; q1 += d.y; }
                    else if ((i & 3) == 2) { p2 += d.x; q2 += d.y; }
                    else                   { p3 += d.x; q3 += d.y; }
                }
            }
            float P = (p0 + p1) + (p2 + p3);
            float Q = (q0 + q1) + (q2 + q3);
            P += __shfl_xor(P, 32);    // combine the two half-waves
            Q += __shfl_xor(Q, 32);
            if (half == 0) {
                float inv = 1.0f / (float)max(deg, 1);
                float h0 = P * inv + v.x;
                float h1 = Q * inv + v.y;
                ((float2*)hv)[(size_t)node * 32 + m] = make_float2(h0, h1);
                s1_0 += h0; s1_1 += h1;
                s2_0 += h0 * h0; s2_1 += h1 * h1;
            }
        }
    }

    __shared__ float2 redA[256];
    __shared__ float2 redB[256];
    redA[threadIdx.x] = make_float2(s1_0, s1_1);
    redB[threadIdx.x] = make_float2(s2_0, s2_1);
    __syncthreads();
    if (threadIdx.x < 32) {
        int mm = threadIdx.x;
        float a0=0,a1=0,b0=0,b1=0;
        for (int w = 0; w < 4; ++w) {
            float2 A = redA[w * 64 + mm]; a0 += A.x; a1 += A.y;
            float2 B = redB[w * 64 + mm]; b0 += B.x; b1 += B.y;
        }
        float* base = sumsR + (size_t)(blockIdx.x & (NCOPY - 1)) * 128;
        atomicAdd(&base[2 * mm], a0);       atomicAdd(&base[2 * mm + 1], a1);
        atomicAdd(&base[64 + 2 * mm], b0);  atomicAdd(&base[64 + 2 * mm + 1], b1);
    }
}

// ===========================================================================
// dense2_bn (R25 proven): BN finalize sums the 32 replicated stat copies.
// ===========================================================================
__global__ __launch_bounds__(256) void dense2_bn_kernel(
    const float* __restrict__ h, const float* __restrict__ sumsR,
    const float* __restrict__ gamma, const float* __restrict__ beta,
    const float* __restrict__ W2l, const float* __restrict__ W2r,
    const float* __restrict__ b2,
    unsigned char* __restrict__ t40, float* __restrict__ out)
{
    __shared__ float wlT[64 * 65];
    __shared__ float wrT[64 * 65];
    for (int idx = threadIdx.x; idx < 2560; idx += 256) {
        int f = idx >> 6, k = idx & 63;      // f < 40
        wlT[k * 65 + f] = W2l[idx];
        wrT[k * 65 + f] = W2r[idx];
    }
    __syncthreads();

    int f  = threadIdx.x & 63;
    int wv = threadIdx.x >> 6;
    int fc = (f < 40) ? f : 39;
    float wl[64], wr[64];
#pragma unroll
    for (int k = 0; k < 64; ++k) {
        wl[k] = wlT[k * 65 + fc];
        wr[k] = wrT[k * 65 + fc];
    }
    float bias = b2[fc];

    // BN finalize: reduce 32 replicated copies, then normalize constants
    float s = 0.f, q = 0.f;
#pragma unroll
    for (int c = 0; c < NCOPY; ++c) {
        s += sumsR[c * 128 + f];
        q += sumsR[c * 128 + 64 + f];
    }
    float inv_n = 1.0f / (float)N_NODES;
    float mu  = s * inv_n;
    float var = q * inv_n - mu * mu;
    float rs  = rsqrtf(var + BN_EPS);
    float sc  = gamma[f] * rs;
    float sh  = beta[f] - mu * sc;

    int node0 = blockIdx.x * 64;

    for (int nn = 0; nn < 16; ++nn) {
        int node = node0 + nn * 4 + wv;          // wave-uniform
        if (node < N_NODES) {
            float hvv = h[(size_t)node * 64 + f];
            float hn  = fmaxf(hvv * sc + sh, 0.f);   // BN + ReLU fused
            float ta = 0.f, ra = bias;
#pragma unroll
            for (int k = 0; k < 64; ++k) {
                float hb = bcast(hn, k);
                ta += hb * wl[k];
                ra += hb * wr[k];
            }
            if (f < 40) {
                t40[(size_t)node * 64 + f] = f2fp8(ta);
                out[(size_t)node * 40 + f] = ra;
            }
        }
    }
}

// ===========================================================================
// gather2 v11 (R24 proven): pipelined inner structure; 16 nodes/block.
// ===========================================================================
__global__ __launch_bounds__(256) void gather2_kernel(
    const unsigned int* __restrict__ t40, const int* __restrict__ cnt,
    const int* __restrict__ nbrf, float* __restrict__ out)
{
    __shared__ int sdeg[16];
    int node0 = blockIdx.x * 16;
    if (threadIdx.x < 16) {
        int n = node0 + threadIdx.x;
        sdeg[threadIdx.x] = (n < N_NODES) ? min(cnt[n], CAP) : 0;
    }
    __syncthreads();

    int lane = threadIdx.x & 63;
    int q    = lane >> 4;          // quarter 0..3
    int m    = lane & 15;          // dword in row; cl<10 used
    int cl   = (m < 10) ? m : 9;
    int wv   = threadIdx.x >> 6;

    int dA = sdeg[wv], dB = sdeg[wv + 4];
    int idA = nbrf[(size_t)min(node0 + wv,     N_NODES - 1) * CAP + min(lane, max(dA, 1) - 1)];
    int idB = nbrf[(size_t)min(node0 + wv + 4, N_NODES - 1) * CAP + min(lane, max(dB, 1) - 1)];

    unsigned int r0A[4], r1A[4], r0B[4], r1B[4];
    {
        int cnt0 = dA;
#pragma unroll
        for (int i = 0; i < 4; ++i) {
            int e   = 4 * i + q;
            int ide = __shfl(idA, max(min(e, cnt0 - 1), 0));
            r0A[i] = t40[(size_t)ide * 16 + cl];
        }
        if (cnt0 > 16) {
#pragma unroll
            for (int i = 0; i < 4; ++i) {
                int e   = 16 + 4 * i + q;
                int ide = __shfl(idA, min(e, cnt0 - 1));
                r1A[i] = t40[(size_t)ide * 16 + cl];
            }
        }
    }

    for (int nn = 0; nn < 4; ++nn) {
        int li   = nn * 4 + wv;
        int node = node0 + li;
        int deg  = sdeg[li];

        int idC = 0;
        if (nn < 2) {
            int lic = li + 8;
            int dc  = sdeg[lic];
            idC = nbrf[(size_t)min(node0 + lic, N_NODES - 1) * CAP + min(lane, max(dc, 1) - 1)];
        }
        if (nn < 3) {
            int cntn = sdeg[li + 4];
#pragma unroll
            for (int i = 0; i < 4; ++i) {
                int e   = 4 * i + q;
                int ide = __shfl(idB, max(min(e, cntn - 1), 0));
                r0B[i] = t40[(size_t)ide * 16 + cl];
            }
            if (cntn > 16) {
#pragma unroll
                for (int i = 0; i < 4; ++i) {
                    int e   = 16 + 4 * i + q;
                    int ide = __shfl(idB, min(e, cntn - 1));
                    r1B[i] = t40[(size_t)ide * 16 + cl];
                }
            }
        }

        if (node < N_NODES) {                    // wave-uniform
            float4 o = make_float4(0.f, 0.f, 0.f, 0.f);
            if (lane < 10)
                o = ((const float4*)out)[(size_t)node * 10 + m];

            float a0=0,a1=0,a2=0,a3=0, b0=0,b1=0,b2=0,b3=0;
            // round 0 from prefetched regs
#pragma unroll
            for (int i = 0; i < 4; ++i) {
                int e = 4 * i + q;
                unsigned int w = (e < deg) ? r0A[i] : 0u;
                v2f dlo = fp8x2<false>(w);
                v2f dhi = fp8x2<true>(w);
                if (i & 1) { b0 += dlo.x; b1 += dlo.y; b2 += dhi.x; b3 += dhi.y; }
                else       { a0 += dlo.x; a1 += dlo.y; a2 += dhi.x; a3 += dhi.y; }
            }
            if (deg > 16) {                      // wave-uniform
#pragma unroll
                for (int i = 0; i < 4; ++i) {
                    int e = 16 + 4 * i + q;
                    unsigned int w = (e < deg) ? r1A[i] : 0u;
                    v2f dlo = fp8x2<false>(w);
                    v2f dhi = fp8x2<true>(w);
                    if (i & 1) { b0 += dlo.x; b1 += dlo.y; b2 += dhi.x; b3 += dhi.y; }
                    else       { a0 += dlo.x; a1 += dlo.y; a2 += dhi.x; a3 += dhi.y; }
                }
                for (int r = 32; r < deg; r += 16) {
#pragma unroll
                    for (int i = 0; i < 4; ++i) {
                        int e   = r + 4 * i + q;
                        int ide = __shfl(idA, min(e, deg - 1));
                        unsigned int w = t40[(size_t)ide * 16 + cl];
                        w = (e < deg) ? w : 0u;
                        v2f dlo = fp8x2<false>(w);
                        v2f dhi = fp8x2<true>(w);
                        if (i & 1) { b0 += dlo.x; b1 += dlo.y; b2 += dhi.x; b3 += dhi.y; }
                        else       { a0 += dlo.x; a1 += dlo.y; a2 += dhi.x; a3 += dhi.y; }
                    }
                }
            }
            a0 += b0; a1 += b1; a2 += b2; a3 += b3;
            a0 += __shfl_xor(a0, 16); a0 += __shfl_xor(a0, 32);
            a1 += __shfl_xor(a1, 16); a1 += __shfl_xor(a1, 32);
            a2 += __shfl_xor(a2, 16); a2 += __shfl_xor(a2, 32);
            a3 += __shfl_xor(a3, 16); a3 += __shfl_xor(a3, 32);
            if (lane < 10) {
                float inv = 1.0f / (float)max(deg, 1);
                o.x += a0 * inv;
                o.y += a1 * inv;
                o.z += a2 * inv;
                o.w += a3 * inv;
                ((float4*)out)[(size_t)node * 10 + m] = o;
            }
        }

        idA = idB; idB = idC;
#pragma unroll
        for (int i = 0; i < 4; ++i) { r0A[i] = r0B[i]; r1A[i] = r1B[i]; }
    }
}

extern "C" void kernel_launch(void* const* d_in, const int* in_sizes, int n_in,
                              void* d_out, int out_size, void* d_ws, size_t ws_size,
                              hipStream_t stream)
{
    const float* x     = (const float*)d_in[0];
    const int*   ei    = (const int*)d_in[1];
    const float* W1l   = (const float*)d_in[2];
    const float* W1r   = (const float*)d_in[3];
    const float* b1    = (const float*)d_in[4];
    const float* gamma = (const float*)d_in[5];
    const float* beta  = (const float*)d_in[6];
    const float* W2l   = (const float*)d_in[7];
    const float* W2r   = (const float*)d_in[8];
    const float* b2    = (const float*)d_in[9];
    float* out = (float*)d_out;

    const int4* src4 = (const int4*)ei;              // edge_index[0], 16B-aligned
    const int4* dst4 = (const int4*)(ei + N_EDGES);  // edge_index[1]

    // workspace layout (58.0 MB of 58.8), 64B-aligned arrays:
    // hv[N*64] f32 | sumsR[32][128] f32 (16KB) | bcur 392 | cnt[N] |
    // nbrf[N*64] int | u8/t40[N*64] fp8.
    // binbuf (7.2 MB) lives in d_out -- scratch until dense2 writes out.
    float* ws    = (float*)d_ws;
    float* hv    = ws;                               // 25.6 MB
    float* sumsR = hv + (size_t)N_NODES * 64;        // 32*128 floats
    int* bcur = (int*)(sumsR + NCOPY * 128);         // 392 (391 used)
    int* cnt  = bcur + 392;                          // N
    int* nbrf = cnt + N_NODES;                       // N*64 (25.6 MB)
    unsigned char* u8 = (unsigned char*)(nbrf + (size_t)N_NODES * 64);  // 6.4 MB
    unsigned char* t40 = u8;
    unsigned int* binbuf = (unsigned int*)d_out;     // 391*4608*4 = 7.2 MB

    dim3 blk(256);

    // zero sumsR | bcur (cnt written exactly by binB): (4096+392)*4 B
    (void)hipMemsetAsync(sumsR, 0, (size_t)(NCOPY * 128 + 392) * 4, stream);

    int dblocks = (N_NODES + 63) / 64;

    // ---- edge radix partition (391 coarse bins) ----
    binA_kernel<<<391, 1024, 0, stream>>>(src4, dst4, bcur, binbuf);

    // ---- per-bin bucket build (LDS atomics) + layer-1 dense (MFMA), FUSED ----
    binB_dense1_kernel<<<NBINS + D1B, blk, 0, stream>>>(
        binbuf, bcur, cnt, nbrf, x, W1l, W1r, b1, u8, hv);

    // ---- layer-1 gather: 16 nodes/block, grid 6250; de-contended stats ----
    gather1_bn_kernel<<<G_BLOCKS, blk, 0, stream>>>(
        (const unsigned short*)u8, cnt, nbrf, hv, sumsR);

    // ---- layer 2 (BN finalize from 32 copies + BN+ReLU fused) ----
    dense2_bn_kernel<<<dblocks, blk, 0, stream>>>(
        hv, sumsR, gamma, beta, W2l, W2r, b2, t40, out);
    gather2_kernel<<<G_BLOCKS, blk, 0, stream>>>(
        (const unsigned int*)t40, cnt, nbrf, out);
}

// Round 14
// 225.188 us; speedup vs baseline: 2.6557x; 1.1768x over previous
//
#include <hip/hip_runtime.h>
#include <hip/hip_fp8.h>

#define N_NODES 100000
#define N_EDGES 1600000
#define BN_EPS 1e-5f
#define E4 400000        // N_EDGES / 4 (int4 count)
#define CAP 64           // bucket capacity; P(deg>64) ~ 1e-20/node (Poisson 16)
#define NBINS 391        // bins of 256 nodes: bin = dst >> 8 (max 99999>>8 = 390)
#define BINCAP 4608      // mean 4096 + 8 sigma
#define BIN_MASK 255
#define G_BLOCKS 6250    // gathers: 16 nodes/block (exact: 6250*16 = 100000)
#define NCOPY 32         // replicated BN-stat accumulators (contention /32)
#define D1B 391          // dense blocks: 256 nodes each (391*256 = 100096)

typedef float v2f __attribute__((ext_vector_type(2)));
typedef __attribute__((ext_vector_type(8))) short bf16x8;   // 8 bf16 (4 VGPRs)
typedef __attribute__((ext_vector_type(4))) float f32x4;

// broadcast lane k's value (readlane). Wave-uniform control flow ONLY.
__device__ __forceinline__ float bcast(float v, int k) {
    return __uint_as_float(__builtin_amdgcn_readlane(__float_as_uint(v), k));
}
__device__ __forceinline__ unsigned short f2bf(float x) {   // round-nearest-even
    unsigned int u = __float_as_uint(x);
    return (unsigned short)((u + 0x7FFF + ((u >> 16) & 1)) >> 16);
}
__device__ __forceinline__ bf16x8 pack8(float4 a, float4 b) {
    bf16x8 r;
    r[0] = (short)f2bf(a.x); r[1] = (short)f2bf(a.y);
    r[2] = (short)f2bf(a.z); r[3] = (short)f2bf(a.w);
    r[4] = (short)f2bf(b.x); r[5] = (short)f2bf(b.y);
    r[6] = (short)f2bf(b.z); r[7] = (short)f2bf(b.w);
    return r;
}
// fp8 e4m3 encode (cold path: once per element in the dense kernels)
__device__ __forceinline__ unsigned char f2fp8(float x) {
    return (unsigned char)__hip_cvt_float_to_fp8(x, __HIP_SATFINITE, __HIP_E4M3);
}
// HW packed decode: 2 x fp8(e4m3) -> 2 x f32 in ONE VALU instruction.
template <bool HI>
__device__ __forceinline__ v2f fp8x2(unsigned int w) {
#if __has_builtin(__builtin_amdgcn_cvt_pk_f32_fp8)
    return __builtin_amdgcn_cvt_pk_f32_fp8((int)w, HI);
#else
    unsigned int b = HI ? (w >> 16) : w;
    __half_raw h0 = __hip_cvt_fp8_to_halfraw((__hip_fp8_storage_t)(b & 0xFF), __HIP_E4M3);
    __half_raw h1 = __hip_cvt_fp8_to_halfraw((__hip_fp8_storage_t)((b >> 8) & 0xFF), __HIP_E4M3);
    v2f r; r.x = __half2float(__half(h0)); r.y = __half2float(__half(h1));
    return r;
#endif
}

// ===========================================================================
// binA (R22 proven): radix partition into 391 coarse bins; LDS counting +
// one bulk global claim per bin per block. binbuf lives in d_out.
// ===========================================================================
__global__ __launch_bounds__(1024) void binA_kernel(
    const int4* __restrict__ src4, const int4* __restrict__ dst4,
    int* __restrict__ bcur, unsigned int* __restrict__ binbuf)
{
    __shared__ int lcnt[NBINS];
    __shared__ int lbase[NBINS];
    int tid = threadIdx.x;
    if (tid < NBINS) lcnt[tid] = 0;
    __syncthreads();

    int i = blockIdx.x * 1024 + tid;
    int4 d, s;
    int b0 = 0, b1 = 0, b2 = 0, b3 = 0, r0 = 0, r1 = 0, r2 = 0, r3 = 0;
    bool valid = (i < E4);
    if (valid) {
        d = dst4[i]; s = src4[i];
        b0 = d.x >> 8; r0 = atomicAdd(&lcnt[b0], 1);
        b1 = d.y >> 8; r1 = atomicAdd(&lcnt[b1], 1);
        b2 = d.z >> 8; r2 = atomicAdd(&lcnt[b2], 1);
        b3 = d.w >> 8; r3 = atomicAdd(&lcnt[b3], 1);
    }
    __syncthreads();
    if (tid < NBINS && lcnt[tid] > 0)
        lbase[tid] = atomicAdd(&bcur[tid], lcnt[tid]);
    __syncthreads();
    if (valid) {
        int p;
        p = lbase[b0] + r0; if (p < BINCAP) binbuf[(size_t)b0 * BINCAP + p] = ((unsigned)s.x << 8) | (unsigned)(d.x & BIN_MASK);
        p = lbase[b1] + r1; if (p < BINCAP) binbuf[(size_t)b1 * BINCAP + p] = ((unsigned)s.y << 8) | (unsigned)(d.y & BIN_MASK);
        p = lbase[b2] + r2; if (p < BINCAP) binbuf[(size_t)b2 * BINCAP + p] = ((unsigned)s.z << 8) | (unsigned)(d.z & BIN_MASK);
        p = lbase[b3] + r3; if (p < BINCAP) binbuf[(size_t)b3 * BINCAP + p] = ((unsigned)s.w << 8) | (unsigned)(d.w & BIN_MASK);
    }
}

// ===========================================================================
// binB + dense1 FUSED (R26 proven): dense1 via bf16 MFMA; binB via LDS
// slot counters.
// ===========================================================================
__global__ __launch_bounds__(256) void binB_dense1_kernel(
    const unsigned int* __restrict__ binbuf, const int* __restrict__ bcur,
    int* __restrict__ cnt, int* __restrict__ nbrf,
    const float* __restrict__ x, const float* __restrict__ W1l,
    const float* __restrict__ W1r, const float* __restrict__ b1,
    unsigned char* __restrict__ u8, float* __restrict__ hv)
{
    if (blockIdx.x < NBINS) {
        // ---- binB role: per-bin bucket build with LDS slot counters ----
        __shared__ int lc[256];
        int tid = threadIdx.x;
        lc[tid] = 0;
        __syncthreads();
        int bin = blockIdx.x;
        int n = min(bcur[bin], BINCAP);
        for (int i = tid; i < n; i += 256) {
            unsigned int e = binbuf[(size_t)bin * BINCAP + i];
            int dl  = (int)(e & BIN_MASK);
            int src = (int)(e >> 8);
            int slot = atomicAdd(&lc[dl], 1);          // LDS atomic
            if (slot < CAP)
                nbrf[((size_t)(bin * 256 + dl)) * CAP + slot] = src;
        }
        __syncthreads();
        int node = bin * 256 + tid;
        if (node < N_NODES) {
            int c = min(lc[tid], CAP);
            cnt[node] = c;
            if (c == 0) nbrf[(size_t)node * CAP] = 0;  // safe id for deg==0
        }
        return;
    }

    // ---- dense1 role (MFMA) ----
    int lane = threadIdx.x & 63;
    int wv   = threadIdx.x >> 6;
    int lr   = lane & 15;          // A-load row / B col / C col
    int lk   = lane >> 4;          // k-group (8 elements each)

    // preload weight fragments: Bf[mat][ftile][khalf]; W rows are B^T frags
    bf16x8 Bf[2][4][2];
#pragma unroll
    for (int mat = 0; mat < 2; ++mat) {
        const float* W = mat ? W1r : W1l;
#pragma unroll
        for (int ft = 0; ft < 4; ++ft) {
#pragma unroll
            for (int kh = 0; kh < 2; ++kh) {
                const float* p = W + (size_t)(ft * 16 + lr) * 64 + kh * 32 + lk * 8;
                Bf[mat][ft][kh] = pack8(*(const float4*)p, *(const float4*)(p + 4));
            }
        }
    }
    float b1v[4];
#pragma unroll
    for (int ft = 0; ft < 4; ++ft) b1v[ft] = b1[ft * 16 + lr];

    int nb = (blockIdx.x - NBINS) * 256;

    for (int it = 0; it < 4; ++it) {
        int n0 = nb + it * 64 + wv * 16;
        int arow = min(n0 + lr, N_NODES - 1);
        const float* xp = x + (size_t)arow * 64 + lk * 8;
        bf16x8 a0 = pack8(*(const float4*)xp,        *(const float4*)(xp + 4));
        bf16x8 a1 = pack8(*(const float4*)(xp + 32), *(const float4*)(xp + 36));

#pragma unroll
        for (int ft = 0; ft < 4; ++ft) {
            f32x4 Cl = {0.f, 0.f, 0.f, 0.f};
            f32x4 Cr = {0.f, 0.f, 0.f, 0.f};
            Cl = __builtin_amdgcn_mfma_f32_16x16x32_bf16(a0, Bf[0][ft][0], Cl, 0, 0, 0);
            Cl = __builtin_amdgcn_mfma_f32_16x16x32_bf16(a1, Bf[0][ft][1], Cl, 0, 0, 0);
            Cr = __builtin_amdgcn_mfma_f32_16x16x32_bf16(a0, Bf[1][ft][0], Cr, 0, 0, 0);
            Cr = __builtin_amdgcn_mfma_f32_16x16x32_bf16(a1, Bf[1][ft][1], Cr, 0, 0, 0);
#pragma unroll
            for (int r = 0; r < 4; ++r) {
                int node = n0 + lk * 4 + r;
                if (node < N_NODES) {
                    u8[(size_t)node * 64 + ft * 16 + lr] = f2fp8(Cl[r]);
                    hv[(size_t)node * 64 + ft * 16 + lr] = Cr[r] + b1v[ft];
                }
            }
        }
    }
}

// ===========================================================================
// gather1_bn v15 (R25 proven): 16-node/block occupancy structure with
// de-contended BN stats (sumsR[blockIdx&31][128]).
// ===========================================================================
__global__ __launch_bounds__(256) void gather1_bn_kernel(
    const unsigned short* __restrict__ u16, const int* __restrict__ cnt,
    const int* __restrict__ nbrf, float* __restrict__ hv,
    float* __restrict__ sumsR)
{
    __shared__ int sdeg[16];
    int node0 = blockIdx.x * 16;
    if (threadIdx.x < 16) {
        int n = node0 + threadIdx.x;
        sdeg[threadIdx.x] = (n < N_NODES) ? min(cnt[n], CAP) : 0;
    }
    __syncthreads();

    int lane = threadIdx.x & 63;
    int m    = lane & 31;
    int half = lane >> 5;
    int wv   = threadIdx.x >> 6;
    float s1_0 = 0.f, s1_1 = 0.f, s2_0 = 0.f, s2_1 = 0.f;

    // prefetch ids for the first node (lane clamped to written slots)
    int d0  = sdeg[wv];
    int idn = nbrf[(size_t)min(node0 + wv, N_NODES - 1) * CAP + min(lane, max(d0, 1) - 1)];

    for (int nn = 0; nn < 4; ++nn) {
        int li   = nn * 4 + wv;
        int node = node0 + li;
        int deg  = sdeg[li];
        int id   = idn;                       // ids for this node

        // prefetch next node's ids while this node's rows load/decode
        if (nn < 3) {
            int lin = li + 4;
            int dn  = sdeg[lin];
            idn = nbrf[(size_t)min(node0 + lin, N_NODES - 1) * CAP + min(lane, max(dn, 1) - 1)];
        }

        if (node < N_NODES) {                    // wave-uniform
            // hoisted hv read: overlaps with the gather latency below
            float2 v = make_float2(0.f, 0.f);
            if (half == 0)
                v = ((const float2*)hv)[(size_t)node * 32 + m];

            float p0=0,p1=0,p2=0,p3=0,q0=0,q1=0,q2=0,q3=0;
            for (int r = 0; r < deg; r += 16) {   // wave-uniform trips; deg<=64
#pragma unroll
                for (int i = 0; i < 8; ++i) {
                    int e   = r + 2 * i + half;   // < 64 always
                    int ide = __shfl(id, e);      // id from registers
                    unsigned int w = u16[(size_t)ide * 32 + m];
                    w = (e < deg) ? w : 0u;       // mask packed word
                    v2f d = fp8x2<false>(w);      // 1 HW instruction
                    if ((i & 3) == 0)      { p0 += d.x; q0 += d.y; }
                    else if ((i & 3) == 1) { p1 += d.x; q1 += d.y; }
                    else if ((i & 3) == 2) { p2 += d.x; q2 += d.y; }
                    else                   { p3 += d.x; q3 += d.y; }
                }
            }
            float P = (p0 + p1) + (p2 + p3);
            float Q = (q0 + q1) + (q2 + q3);
            P += __shfl_xor(P, 32);    // combine the two half-waves
            Q += __shfl_xor(Q, 32);
            if (half == 0) {
                float inv = 1.0f / (float)max(deg, 1);
                float h0 = P * inv + v.x;
                float h1 = Q * inv + v.y;
                ((float2*)hv)[(size_t)node * 32 + m] = make_float2(h0, h1);
                s1_0 += h0; s1_1 += h1;
                s2_0 += h0 * h0; s2_1 += h1 * h1;
            }
        }
    }

    __shared__ float2 redA[256];
    __shared__ float2 redB[256];
    redA[threadIdx.x] = make_float2(s1_0, s1_1);
    redB[threadIdx.x] = make_float2(s2_0, s2_1);
    __syncthreads();
    if (threadIdx.x < 32) {
        int mm = threadIdx.x;
        float a0=0,a1=0,b0=0,b1=0;
        for (int w = 0; w < 4; ++w) {
            float2 A = redA[w * 64 + mm]; a0 += A.x; a1 += A.y;
            float2 B = redB[w * 64 + mm]; b0 += B.x; b1 += B.y;
        }
        float* base = sumsR + (size_t)(blockIdx.x & (NCOPY - 1)) * 128;
        atomicAdd(&base[2 * mm], a0);       atomicAdd(&base[2 * mm + 1], a1);
        atomicAdd(&base[64 + 2 * mm], b0);  atomicAdd(&base[64 + 2 * mm + 1], b1);
    }
}

// ===========================================================================
// dense2_bn v2 (R27): bf16 MFMA (same pattern as dense1, R12-verified).
// (a) A-operand = relu(h*sc+sh): BN constants finalized once into LDS;
// (b) 40 output features -> 3 ft-tiles of 16, B-frag rows clamped to 39,
//     writes masked to f<40.
// ===========================================================================
__global__ __launch_bounds__(256) void dense2_bn_kernel(
    const float* __restrict__ h, const float* __restrict__ sumsR,
    const float* __restrict__ gamma, const float* __restrict__ beta,
    const float* __restrict__ W2l, const float* __restrict__ W2r,
    const float* __restrict__ b2,
    unsigned char* __restrict__ t40, float* __restrict__ out)
{
    __shared__ float ssc[64];
    __shared__ float ssh[64];
    if (threadIdx.x < 64) {
        int f = threadIdx.x;
        float s = 0.f, q = 0.f;
#pragma unroll
        for (int c = 0; c < NCOPY; ++c) {
            s += sumsR[c * 128 + f];
            q += sumsR[c * 128 + 64 + f];
        }
        float inv_n = 1.0f / (float)N_NODES;
        float mu  = s * inv_n;
        float var = q * inv_n - mu * mu;
        float rs  = rsqrtf(var + BN_EPS);
        float sc  = gamma[f] * rs;
        ssc[f] = sc;
        ssh[f] = beta[f] - mu * sc;
    }
    __syncthreads();

    int lane = threadIdx.x & 63;
    int wv   = threadIdx.x >> 6;
    int lr   = lane & 15;          // B row (output feature mod 16) / C col
    int lk   = lane >> 4;          // k-group (8 elements each)

    // per-lane BN constants for its two k-halves
    float scA[8], shA[8], scB[8], shB[8];
#pragma unroll
    for (int j = 0; j < 8; ++j) {
        scA[j] = ssc[lk * 8 + j];      shA[j] = ssh[lk * 8 + j];
        scB[j] = ssc[32 + lk * 8 + j]; shB[j] = ssh[32 + lk * 8 + j];
    }

    // preload weight fragments: rows >= 40 clamped (cols 40..47 masked on write)
    bf16x8 Bt[3][2], Bo[3][2];
#pragma unroll
    for (int ft = 0; ft < 3; ++ft) {
        int row = min(ft * 16 + lr, 39);
#pragma unroll
        for (int kh = 0; kh < 2; ++kh) {
            const float* pl = W2l + (size_t)row * 64 + kh * 32 + lk * 8;
            const float* pr = W2r + (size_t)row * 64 + kh * 32 + lk * 8;
            Bt[ft][kh] = pack8(*(const float4*)pl, *(const float4*)(pl + 4));
            Bo[ft][kh] = pack8(*(const float4*)pr, *(const float4*)(pr + 4));
        }
    }
    float b2v[3];
#pragma unroll
    for (int ft = 0; ft < 3; ++ft) b2v[ft] = b2[min(ft * 16 + lr, 39)];

    int nb = blockIdx.x * 256;

    for (int it = 0; it < 4; ++it) {
        int n0 = nb + it * 64 + wv * 16;
        int arow = min(n0 + lr, N_NODES - 1);
        const float* hp = h + (size_t)arow * 64 + lk * 8;
        float4 h0a = *(const float4*)hp,        h0b = *(const float4*)(hp + 4);
        float4 h1a = *(const float4*)(hp + 32), h1b = *(const float4*)(hp + 36);
        // BN + ReLU per element, then pack to bf16
        float4 n0a, n0b, n1a, n1b;
        n0a.x = fmaxf(h0a.x * scA[0] + shA[0], 0.f);
        n0a.y = fmaxf(h0a.y * scA[1] + shA[1], 0.f);
        n0a.z = fmaxf(h0a.z * scA[2] + shA[2], 0.f);
        n0a.w = fmaxf(h0a.w * scA[3] + shA[3], 0.f);
        n0b.x = fmaxf(h0b.x * scA[4] + shA[4], 0.f);
        n0b.y = fmaxf(h0b.y * scA[5] + shA[5], 0.f);
        n0b.z = fmaxf(h0b.z * scA[6] + shA[6], 0.f);
        n0b.w = fmaxf(h0b.w * scA[7] + shA[7], 0.f);
        n1a.x = fmaxf(h1a.x * scB[0] + shB[0], 0.f);
        n1a.y = fmaxf(h1a.y * scB[1] + shB[1], 0.f);
        n1a.z = fmaxf(h1a.z * scB[2] + shB[2], 0.f);
        n1a.w = fmaxf(h1a.w * scB[3] + shB[3], 0.f);
        n1b.x = fmaxf(h1b.x * scB[4] + shB[4], 0.f);
        n1b.y = fmaxf(h1b.y * scB[5] + shB[5], 0.f);
        n1b.z = fmaxf(h1b.z * scB[6] + shB[6], 0.f);
        n1b.w = fmaxf(h1b.w * scB[7] + shB[7], 0.f);
        bf16x8 a0 = pack8(n0a, n0b);
        bf16x8 a1 = pack8(n1a, n1b);

#pragma unroll
        for (int ft = 0; ft < 3; ++ft) {
            f32x4 Ct = {0.f, 0.f, 0.f, 0.f};
            f32x4 Co = {0.f, 0.f, 0.f, 0.f};
            Ct = __builtin_amdgcn_mfma_f32_16x16x32_bf16(a0, Bt[ft][0], Ct, 0, 0, 0);
            Ct = __builtin_amdgcn_mfma_f32_16x16x32_bf16(a1, Bt[ft][1], Ct, 0, 0, 0);
            Co = __builtin_amdgcn_mfma_f32_16x16x32_bf16(a0, Bo[ft][0], Co, 0, 0, 0);
            Co = __builtin_amdgcn_mfma_f32_16x16x32_bf16(a1, Bo[ft][1], Co, 0, 0, 0);
            int f = ft * 16 + lr;
#pragma unroll
            for (int r = 0; r < 4; ++r) {
                int node = n0 + lk * 4 + r;
                if (node < N_NODES && f < 40) {
                    t40[(size_t)node * 64 + f] = f2fp8(Ct[r]);
                    out[(size_t)node * 40 + f] = Co[r] + b2v[ft];
                }
            }
        }
    }
}

// ===========================================================================
// gather2 v11 (R24 proven): pipelined inner structure; 16 nodes/block.
// ===========================================================================
__global__ __launch_bounds__(256) void gather2_kernel(
    const unsigned int* __restrict__ t40, const int* __restrict__ cnt,
    const int* __restrict__ nbrf, float* __restrict__ out)
{
    __shared__ int sdeg[16];
    int node0 = blockIdx.x * 16;
    if (threadIdx.x < 16) {
        int n = node0 + threadIdx.x;
        sdeg[threadIdx.x] = (n < N_NODES) ? min(cnt[n], CAP) : 0;
    }
    __syncthreads();

    int lane = threadIdx.x & 63;
    int q    = lane >> 4;          // quarter 0..3
    int m    = lane & 15;          // dword in row; cl<10 used
    int cl   = (m < 10) ? m : 9;
    int wv   = threadIdx.x >> 6;

    int dA = sdeg[wv], dB = sdeg[wv + 4];
    int idA = nbrf[(size_t)min(node0 + wv,     N_NODES - 1) * CAP + min(lane, max(dA, 1) - 1)];
    int idB = nbrf[(size_t)min(node0 + wv + 4, N_NODES - 1) * CAP + min(lane, max(dB, 1) - 1)];

    unsigned int r0A[4], r1A[4], r0B[4], r1B[4];
    {
        int cnt0 = dA;
#pragma unroll
        for (int i = 0; i < 4; ++i) {
            int e   = 4 * i + q;
            int ide = __shfl(idA, max(min(e, cnt0 - 1), 0));
            r0A[i] = t40[(size_t)ide * 16 + cl];
        }
        if (cnt0 > 16) {
#pragma unroll
            for (int i = 0; i < 4; ++i) {
                int e   = 16 + 4 * i + q;
                int ide = __shfl(idA, min(e, cnt0 - 1));
                r1A[i] = t40[(size_t)ide * 16 + cl];
            }
        }
    }

    for (int nn = 0; nn < 4; ++nn) {
        int li   = nn * 4 + wv;
        int node = node0 + li;
        int deg  = sdeg[li];

        int idC = 0;
        if (nn < 2) {
            int lic = li + 8;
            int dc  = sdeg[lic];
            idC = nbrf[(size_t)min(node0 + lic, N_NODES - 1) * CAP + min(lane, max(dc, 1) - 1)];
        }
        if (nn < 3) {
            int cntn = sdeg[li + 4];
#pragma unroll
            for (int i = 0; i < 4; ++i) {
                int e   = 4 * i + q;
                int ide = __shfl(idB, max(min(e, cntn - 1), 0));
                r0B[i] = t40[(size_t)ide * 16 + cl];
            }
            if (cntn > 16) {
#pragma unroll
                for (int i = 0; i < 4; ++i) {
                    int e   = 16 + 4 * i + q;
                    int ide = __shfl(idB, min(e, cntn - 1));
                    r1B[i] = t40[(size_t)ide * 16 + cl];
                }
            }
        }

        if (node < N_NODES) {                    // wave-uniform
            float4 o = make_float4(0.f, 0.f, 0.f, 0.f);
            if (lane < 10)
                o = ((const float4*)out)[(size_t)node * 10 + m];

            float a0=0,a1=0,a2=0,a3=0, b0=0,b1=0,b2=0,b3=0;
            // round 0 from prefetched regs
#pragma unroll
            for (int i = 0; i < 4; ++i) {
                int e = 4 * i + q;
                unsigned int w = (e < deg) ? r0A[i] : 0u;
                v2f dlo = fp8x2<false>(w);
                v2f dhi = fp8x2<true>(w);
                if (i & 1) { b0 += dlo.x; b1 += dlo.y; b2 += dhi.x; b3 += dhi.y; }
                else       { a0 += dlo.x; a1 += dlo.y; a2 += dhi.x; a3 += dhi.y; }
            }
            if (deg > 16) {                      // wave-uniform
#pragma unroll
                for (int i = 0; i < 4; ++i) {
                    int e = 16 + 4 * i + q;
                    unsigned int w = (e < deg) ? r1A[i] : 0u;
                    v2f dlo = fp8x2<false>(w);
                    v2f dhi = fp8x2<true>(w);
                    if (i & 1) { b0 += dlo.x; b1 += dlo.y; b2 += dhi.x; b3 += dhi.y; }
                    else       { a0 += dlo.x; a1 += dlo.y; a2 += dhi.x; a3 += dhi.y; }
                }
                for (int r = 32; r < deg; r += 16) {
#pragma unroll
                    for (int i = 0; i < 4; ++i) {
                        int e   = r + 4 * i + q;
                        int ide = __shfl(idA, min(e, deg - 1));
                        unsigned int w = t40[(size_t)ide * 16 + cl];
                        w = (e < deg) ? w : 0u;
                        v2f dlo = fp8x2<false>(w);
                        v2f dhi = fp8x2<true>(w);
                        if (i & 1) { b0 += dlo.x; b1 += dlo.y; b2 += dhi.x; b3 += dhi.y; }
                        else       { a0 += dlo.x; a1 += dlo.y; a2 += dhi.x; a3 += dhi.y; }
                    }
                }
            }
            a0 += b0; a1 += b1; a2 += b2; a3 += b3;
            a0 += __shfl_xor(a0, 16); a0 += __shfl_xor(a0, 32);
            a1 += __shfl_xor(a1, 16); a1 += __shfl_xor(a1, 32);
            a2 += __shfl_xor(a2, 16); a2 += __shfl_xor(a2, 32);
            a3 += __shfl_xor(a3, 16); a3 += __shfl_xor(a3, 32);
            if (lane < 10) {
                float inv = 1.0f / (float)max(deg, 1);
                o.x += a0 * inv;
                o.y += a1 * inv;
                o.z += a2 * inv;
                o.w += a3 * inv;
                ((float4*)out)[(size_t)node * 10 + m] = o;
            }
        }

        idA = idB; idB = idC;
#pragma unroll
        for (int i = 0; i < 4; ++i) { r0A[i] = r0B[i]; r1A[i] = r1B[i]; }
    }
}

extern "C" void kernel_launch(void* const* d_in, const int* in_sizes, int n_in,
                              void* d_out, int out_size, void* d_ws, size_t ws_size,
                              hipStream_t stream)
{
    const float* x     = (const float*)d_in[0];
    const int*   ei    = (const int*)d_in[1];
    const float* W1l   = (const float*)d_in[2];
    const float* W1r   = (const float*)d_in[3];
    const float* b1    = (const float*)d_in[4];
    const float* gamma = (const float*)d_in[5];
    const float* beta  = (const float*)d_in[6];
    const float* W2l   = (const float*)d_in[7];
    const float* W2r   = (const float*)d_in[8];
    const float* b2    = (const float*)d_in[9];
    float* out = (float*)d_out;

    const int4* src4 = (const int4*)ei;              // edge_index[0], 16B-aligned
    const int4* dst4 = (const int4*)(ei + N_EDGES);  // edge_index[1]

    // workspace layout (58.0 MB of 58.8), 64B-aligned arrays:
    // hv[N*64] f32 | sumsR[32][128] f32 (16KB) | bcur 392 | cnt[N] |
    // nbrf[N*64] int | u8/t40[N*64] fp8.
    // binbuf (7.2 MB) lives in d_out -- scratch until dense2 writes out.
    float* ws    = (float*)d_ws;
    float* hv    = ws;                               // 25.6 MB
    float* sumsR = hv + (size_t)N_NODES * 64;        // 32*128 floats
    int* bcur = (int*)(sumsR + NCOPY * 128);         // 392 (391 used)
    int* cnt  = bcur + 392;                          // N
    int* nbrf = cnt + N_NODES;                       // N*64 (25.6 MB)
    unsigned char* u8 = (unsigned char*)(nbrf + (size_t)N_NODES * 64);  // 6.4 MB
    unsigned char* t40 = u8;
    unsigned int* binbuf = (unsigned int*)d_out;     // 391*4608*4 = 7.2 MB

    dim3 blk(256);

    // zero sumsR | bcur (cnt written exactly by binB): (4096+392)*4 B
    (void)hipMemsetAsync(sumsR, 0, (size_t)(NCOPY * 128 + 392) * 4, stream);

    // ---- edge radix partition (391 coarse bins) ----
    binA_kernel<<<391, 1024, 0, stream>>>(src4, dst4, bcur, binbuf);

    // ---- per-bin bucket build (LDS atomics) + layer-1 dense (MFMA), FUSED ----
    binB_dense1_kernel<<<NBINS + D1B, blk, 0, stream>>>(
        binbuf, bcur, cnt, nbrf, x, W1l, W1r, b1, u8, hv);

    // ---- layer-1 gather: 16 nodes/block, grid 6250; de-contended stats ----
    gather1_bn_kernel<<<G_BLOCKS, blk, 0, stream>>>(
        (const unsigned short*)u8, cnt, nbrf, hv, sumsR);

    // ---- layer 2 (BN finalize in LDS + BN+ReLU + MFMA matmuls) ----
    dense2_bn_kernel<<<D1B, blk, 0, stream>>>(
        hv, sumsR, gamma, beta, W2l, W2r, b2, t40, out);
    gather2_kernel<<<G_BLOCKS, blk, 0, stream>>>(
        (const unsigned int*)t40, cnt, nbrf, out);
}